// Round 1
// baseline (881.178 us; speedup 1.0000x reference)
//
#include <hip/hip_runtime.h>
#include <math.h>

#define NN 16384
#define EE 65536
#define BB 512
#define HH 64
#define NHEADS 16
#define KI 3
#define VV 32000

typedef unsigned short us_t;
typedef unsigned int u32_t;

__device__ __forceinline__ float bf2f(unsigned int u) {
  return __uint_as_float((u & 0xffffu) << 16);
}
__device__ __forceinline__ unsigned short f2bf(float f) {
  unsigned int x = __float_as_uint(f);
  unsigned int r = (x + 0x7fffu + ((x >> 16) & 1u)) >> 16;
  return (unsigned short)r;
}
__device__ __forceinline__ float wsum(float v) {
#pragma unroll
  for (int o = 32; o; o >>= 1) v += __shfl_xor(v, o, 64);
  return v;
}
__device__ __forceinline__ float lrelu(float x) { return x > 0.f ? x : 0.2f * x; }

// ---------------- dtype probe + conversion ----------------
__global__ void k_detect(const void* emb, int* flag) {
  if (threadIdx.x == 0 && blockIdx.x == 0) {
    const us_t* u = (const us_t*)emb;
    int ok = 1;
    for (int i = 0; i < 128; i++) {
      float v = bf2f((unsigned int)u[i]);
      if (!(fabsf(v) <= 0.13f)) { ok = 0; break; }
    }
    *flag = ok;  // 1 => inputs are bf16, 0 => f32
  }
}

__global__ void k_cvt(const void* in, float* outp, int n, const int* flag) {
  int i = blockIdx.x * blockDim.x + threadIdx.x;
  if (i >= n) return;
  if (*flag)
    outp[i] = bf2f((unsigned int)((const us_t*)in)[i]);
  else
    outp[i] = ((const float*)in)[i];
}

// ---------------- embedding gather + interest softmax ----------------
__global__ void k_embed(const int* __restrict__ x, const float* __restrict__ emb,
                        const float* __restrict__ w_int,
                        float* __restrict__ e, float* __restrict__ g) {
  int gid = blockIdx.x * blockDim.x + threadIdx.x;
  int n = gid >> 6, lane = gid & 63;
  if (n >= NN) return;
  float v = emb[(size_t)x[n] * 64 + lane];
  e[(size_t)n * 64 + lane] = v;
  float t0 = v * w_int[lane * 3 + 0];
  float t1 = v * w_int[lane * 3 + 1];
  float t2 = v * w_int[lane * 3 + 2];
  t0 = wsum(t0); t1 = wsum(t1); t2 = wsum(t2);
  if (lane == 0) {
    float l0 = t0 / 0.1f, l1 = t1 / 0.1f, l2 = t2 / 0.1f;
    float m = fmaxf(l0, fmaxf(l1, l2));
    float p0 = expf(l0 - m), p1 = expf(l1 - m), p2 = expf(l2 - m);
    float inv = 1.0f / (p0 + p1 + p2);
    g[n * 4 + 0] = p0 * inv; g[n * 4 + 1] = p1 * inv;
    g[n * 4 + 2] = p2 * inv; g[n * 4 + 3] = 0.f;
  }
}

// ---------------- CSR build (edges grouped by dst) ----------------
__global__ void k_count(const int* __restrict__ dst, int* __restrict__ counts) {
  int e = blockIdx.x * blockDim.x + threadIdx.x;
  if (e < EE) atomicAdd(&counts[dst[e]], 1);
}

__global__ void k_scan(const int* __restrict__ counts, int* __restrict__ offsets) {
  __shared__ int part[256];
  __shared__ int excl[257];
  int t = threadIdx.x;
  int base = t * 64;
  int s = 0;
  for (int j = 0; j < 64; j++) s += counts[base + j];
  part[t] = s;
  __syncthreads();
  if (t == 0) {
    int run = 0;
    for (int j = 0; j < 256; j++) { excl[j] = run; run += part[j]; }
    excl[256] = run;
  }
  __syncthreads();
  int run = excl[t];
  for (int j = 0; j < 64; j++) { offsets[base + j] = run; run += counts[base + j]; }
  if (t == 255) offsets[NN] = excl[256];
}

__global__ void k_fill(const int* __restrict__ src, const int* __restrict__ dst,
                       const int* __restrict__ offsets, int* __restrict__ fillpos,
                       int* __restrict__ adj) {
  int e = blockIdx.x * blockDim.x + threadIdx.x;
  if (e < EE) {
    int d = dst[e];
    int pos = offsets[d] + atomicAdd(&fillpos[d], 1);
    adj[pos] = src[e];
  }
}

// ---------------- GAT1 linear: [N,64] @ [64,1024] -> bf16 ----------------
__global__ __launch_bounds__(256) void k_gat1_lin(
    const float* __restrict__ e, const float* __restrict__ g,
    const float* __restrict__ W, int intr, us_t* __restrict__ h_pre) {
  __shared__ float As[64][65];
  __shared__ float Bs[64][128];
  int t = threadIdx.x;
  int row0 = blockIdx.x * 64, col0 = blockIdx.y * 128;
  for (int idx = t; idx < 64 * 64; idx += 256) {
    int r = idx >> 6, k = idx & 63;
    As[r][k] = e[(size_t)(row0 + r) * 64 + k] * g[(row0 + r) * 4 + intr];
  }
  for (int idx = t; idx < 64 * 128; idx += 256) {
    int k = idx >> 7, c = idx & 127;
    Bs[k][c] = W[(size_t)k * 1024 + col0 + c];
  }
  __syncthreads();
  int tc = t >> 4, tr = t & 15;
  float acc[4][8];
#pragma unroll
  for (int r = 0; r < 4; r++)
#pragma unroll
    for (int j = 0; j < 8; j++) acc[r][j] = 0.f;
  for (int k = 0; k < 64; k++) {
    float a[4];
#pragma unroll
    for (int r = 0; r < 4; r++) a[r] = As[tr * 4 + r][k];
    float b[8];
#pragma unroll
    for (int j = 0; j < 8; j++) b[j] = Bs[k][tc * 8 + j];
#pragma unroll
    for (int r = 0; r < 4; r++)
#pragma unroll
      for (int j = 0; j < 8; j++) acc[r][j] += a[r] * b[j];
  }
#pragma unroll
  for (int r = 0; r < 4; r++) {
    u32_t w0 = (u32_t)f2bf(acc[r][0]) | ((u32_t)f2bf(acc[r][1]) << 16);
    u32_t w1 = (u32_t)f2bf(acc[r][2]) | ((u32_t)f2bf(acc[r][3]) << 16);
    u32_t w2 = (u32_t)f2bf(acc[r][4]) | ((u32_t)f2bf(acc[r][5]) << 16);
    u32_t w3 = (u32_t)f2bf(acc[r][6]) | ((u32_t)f2bf(acc[r][7]) << 16);
    uint4* p = (uint4*)&h_pre[(size_t)(row0 + tr * 4 + r) * 1024 + col0 + tc * 8];
    *p = make_uint4(w0, w1, w2, w3);
  }
}

// ---------------- attention coefficients (16 heads) ----------------
__global__ void k_att1(const us_t* __restrict__ h_pre,
                       const float* __restrict__ a_s, const float* __restrict__ a_d,
                       float* __restrict__ asrc, float* __restrict__ adst) {
  int gid = blockIdx.x * blockDim.x + threadIdx.x;
  int w = gid >> 6, lane = gid & 63;
  if (w >= NN * NHEADS) return;
  int n = w >> 4, head = w & 15;
  float h = bf2f((unsigned int)h_pre[(size_t)n * 1024 + head * 64 + lane]);
  float s = h * a_s[head * 64 + lane];
  float d = h * a_d[head * 64 + lane];
  s = wsum(s); d = wsum(d);
  if (lane == 0) { asrc[n * 16 + head] = s; adst[n * 16 + head] = d; }
}

__device__ __forceinline__ void ld_bf4(const us_t* p, float* f) {
  uint2 u = *(const uint2*)p;
  f[0] = bf2f(u.x); f[1] = bf2f(u.x >> 16);
  f[2] = bf2f(u.y); f[3] = bf2f(u.y >> 16);
}

// ---------------- GAT1 edge-softmax aggregation (per dst node) ----------------
__global__ __launch_bounds__(256) void k_gat1_agg(
    const us_t* __restrict__ h_pre,
    const float* __restrict__ asrc, const float* __restrict__ adst,
    const float* __restrict__ g, const float* __restrict__ bias, int intr,
    const int* __restrict__ offsets, const int* __restrict__ adj,
    us_t* __restrict__ h1) {
  __shared__ float m_s[16], den_s[16], ad_s[16];
  int n = blockIdx.x;
  int t = threadIdx.x;
  bool nvalid = g[n * 4 + intr] > (1.0f / 3.0f);
  int beg = offsets[n], end = offsets[n + 1];
  if (t < 16) {
    int head = t;
    float ad = adst[n * 16 + head];
    float l = lrelu(asrc[n * 16 + head] + ad);  // self loop, always valid
    float m = l;
    if (nvalid) {
      for (int j = beg; j < end; j++) {
        int s = adj[j];
        if (g[s * 4 + intr] > (1.0f / 3.0f))
          m = fmaxf(m, lrelu(asrc[s * 16 + head] + ad));
      }
    }
    float den = expf(l - m);
    if (nvalid) {
      for (int j = beg; j < end; j++) {
        int s = adj[j];
        if (g[s * 4 + intr] > (1.0f / 3.0f))
          den += expf(lrelu(asrc[s * 16 + head] + ad) - m);
      }
    }
    m_s[head] = m; den_s[head] = den; ad_s[head] = ad;
  }
  __syncthreads();
  int head = t >> 4, d0 = (t & 15) * 4;
  float m = m_s[head], ad = ad_s[head];
  float acc[4], hv[4];
  {
    float p = expf(lrelu(asrc[n * 16 + head] + ad) - m);
    ld_bf4(&h_pre[(size_t)n * 1024 + head * 64 + d0], hv);
#pragma unroll
    for (int q = 0; q < 4; q++) acc[q] = p * hv[q];
  }
  if (nvalid) {
    for (int j = beg; j < end; j++) {
      int s = adj[j];
      if (g[s * 4 + intr] > (1.0f / 3.0f)) {
        float p = expf(lrelu(asrc[s * 16 + head] + ad) - m);
        ld_bf4(&h_pre[(size_t)s * 1024 + head * 64 + d0], hv);
#pragma unroll
        for (int q = 0; q < 4; q++) acc[q] += p * hv[q];
      }
    }
  }
  float inv = 1.0f / den_s[head];
  u32_t o0, o1;
  {
    float v0 = fmaxf(acc[0] * inv + bias[head * 64 + d0 + 0], 0.f);
    float v1 = fmaxf(acc[1] * inv + bias[head * 64 + d0 + 1], 0.f);
    float v2 = fmaxf(acc[2] * inv + bias[head * 64 + d0 + 2], 0.f);
    float v3 = fmaxf(acc[3] * inv + bias[head * 64 + d0 + 3], 0.f);
    o0 = (u32_t)f2bf(v0) | ((u32_t)f2bf(v1) << 16);
    o1 = (u32_t)f2bf(v2) | ((u32_t)f2bf(v3) << 16);
  }
  *(uint2*)&h1[(size_t)n * 1024 + head * 64 + d0] = make_uint2(o0, o1);
}

// ---------------- GAT2 linear: [N,1024] @ [1024,64] -> f32 ----------------
__global__ __launch_bounds__(256) void k_gat2_lin(
    const us_t* __restrict__ h1, const float* __restrict__ W,
    float* __restrict__ h2pre) {
  __shared__ us_t hs[16][1024];
  int t = threadIdx.x;
  int n0 = blockIdx.x * 16;
  const u32_t* srcp = (const u32_t*)(h1 + (size_t)n0 * 1024);
  u32_t* dstp = (u32_t*)&hs[0][0];
  for (int idx = t; idx < 16 * 512; idx += 256) dstp[idx] = srcp[idx];
  __syncthreads();
  int c = t & 63, rg = t >> 6;
  float acc[4] = {0.f, 0.f, 0.f, 0.f};
  for (int k0 = 0; k0 < 1024; k0 += 8) {
    uint4 hv[4];
#pragma unroll
    for (int q = 0; q < 4; q++) hv[q] = *(const uint4*)&hs[rg + q * 4][k0];
#pragma unroll
    for (int kk = 0; kk < 8; kk++) {
      float wv = W[(size_t)(k0 + kk) * 64 + c];
#pragma unroll
      for (int q = 0; q < 4; q++) {
        u32_t u = ((const u32_t*)&hv[q])[kk >> 1];
        float h = (kk & 1) ? bf2f(u >> 16) : bf2f(u);
        acc[q] += h * wv;
      }
    }
  }
#pragma unroll
  for (int q = 0; q < 4; q++) h2pre[(size_t)(n0 + rg + q * 4) * 64 + c] = acc[q];
}

__global__ void k_att2(const float* __restrict__ h2pre, const float* __restrict__ a_s,
                       const float* __restrict__ a_d, float* __restrict__ a2s,
                       float* __restrict__ a2d) {
  int gid = blockIdx.x * blockDim.x + threadIdx.x;
  int n = gid >> 6, lane = gid & 63;
  if (n >= NN) return;
  float h = h2pre[(size_t)n * 64 + lane];
  float s = h * a_s[lane], d = h * a_d[lane];
  s = wsum(s); d = wsum(d);
  if (lane == 0) { a2s[n] = s; a2d[n] = d; }
}

// ---------------- GAT2 aggregation (1 head) -> sess ----------------
__global__ void k_gat2_agg(const float* __restrict__ h2pre,
                           const float* __restrict__ a2s, const float* __restrict__ a2d,
                           const float* __restrict__ g, const float* __restrict__ b2,
                           int intr, const int* __restrict__ offsets,
                           const int* __restrict__ adj, float* __restrict__ sess) {
  int gid = blockIdx.x * blockDim.x + threadIdx.x;
  int n = gid >> 6, lane = gid & 63;
  if (n >= NN) return;
  bool nvalid = g[n * 4 + intr] > (1.0f / 3.0f);
  float ad = a2d[n];
  float ls = lrelu(a2s[n] + ad);
  float m = ls;
  int beg = offsets[n], end = offsets[n + 1];
  if (nvalid) {
    for (int j = beg; j < end; j++) {
      int s = adj[j];
      if (g[s * 4 + intr] > (1.0f / 3.0f)) m = fmaxf(m, lrelu(a2s[s] + ad));
    }
  }
  float p = expf(ls - m);
  float den = p;
  float acc = p * h2pre[(size_t)n * 64 + lane];
  if (nvalid) {
    for (int j = beg; j < end; j++) {
      int s = adj[j];
      if (g[s * 4 + intr] > (1.0f / 3.0f)) {
        float w2 = expf(lrelu(a2s[s] + ad) - m);
        den += w2;
        acc += w2 * h2pre[(size_t)s * 64 + lane];
      }
    }
  }
  sess[(size_t)n * 192 + intr * 64 + lane] = acc / den + b2[lane];
}

// ---------------- scoring ----------------
__global__ void k_last(const int* __restrict__ batch, int* __restrict__ lasti) {
  int n = blockIdx.x * blockDim.x + threadIdx.x;
  if (n < NN) atomicMax(&lasti[batch[n]], n);
}

__global__ __launch_bounds__(192) void k_vq1(
    const float* __restrict__ sess, const int* __restrict__ lasti,
    const float* __restrict__ W1w, const float* __restrict__ W1b,
    float* __restrict__ vn, float* __restrict__ vq1) {
  __shared__ float row[192];
  int b = blockIdx.x, j = threadIdx.x;
  int li = lasti[b];
  float v = sess[(size_t)li * 192 + j];
  row[j] = v;
  vn[b * 192 + j] = v;
  __syncthreads();
  float acc = W1b[j];
  for (int k = 0; k < 192; k++) acc += row[k] * W1w[k * 192 + j];
  vq1[b * 192 + j] = acc;
}

__global__ __launch_bounds__(192) void k_alpha_sg(
    const float* __restrict__ sess, const float* __restrict__ vq1,
    const int* __restrict__ batch, const float* __restrict__ W2w,
    const float* __restrict__ W2b, const float* __restrict__ qw,
    const float* __restrict__ qb, float* __restrict__ sg) {
  __shared__ float srow[8][192];
  __shared__ float red[192];
  __shared__ float alpha_sh;
  int t = threadIdx.x;
  int n0 = blockIdx.x * 8;
#pragma unroll
  for (int q = 0; q < 8; q++) srow[q][t] = sess[(size_t)(n0 + q) * 192 + t];
  __syncthreads();
  float q2[8];
#pragma unroll
  for (int q = 0; q < 8; q++) q2[q] = W2b[t];
  for (int k = 0; k < 192; k++) {
    float wv = W2w[k * 192 + t];
#pragma unroll
    for (int q = 0; q < 8; q++) q2[q] += srow[q][k] * wv;
  }
  float qwt = qw[t];
  for (int q = 0; q < 8; q++) {
    int n = n0 + q;
    int bq = batch[n];
    float s = 1.0f / (1.0f + expf(-(vq1[bq * 192 + t] + q2[q])));
    red[t] = s * qwt;
    __syncthreads();
    if (t < 64) {
      float r = red[t] + red[t + 64] + red[t + 128];
#pragma unroll
      for (int o = 32; o; o >>= 1) r += __shfl_xor(r, o, 64);
      if (t == 0) alpha_sh = r + qb[0];
    }
    __syncthreads();
    float alpha = alpha_sh;
    atomicAdd(&sg[bq * 192 + t], alpha * srow[q][t]);
    __syncthreads();
  }
}

__global__ __launch_bounds__(192) void k_sh(
    const float* __restrict__ vn, const float* __restrict__ sg,
    const float* __restrict__ W3w, const float* __restrict__ W3b,
    float* __restrict__ sh) {
  __shared__ float row[384];
  int b = blockIdx.x, j = threadIdx.x;
  row[j] = vn[b * 192 + j];
  row[192 + j] = sg[b * 192 + j];
  __syncthreads();
  float acc = W3b[j];
  for (int k = 0; k < 384; k++) acc += row[k] * W3w[k * 192 + j];
  sh[b * 192 + j] = acc;
}

// ---------------- final: s_h @ emb^T, max over K ----------------
__global__ __launch_bounds__(256) void k_final(const float* __restrict__ sh,
                                               const float* __restrict__ emb,
                                               void* __restrict__ out,
                                               const int* __restrict__ flag) {
  __shared__ float shs[96 * 64];
  __shared__ float embt[64][69];
  int t = threadIdx.x;
  int v0 = blockIdx.x * 64;
  int s0 = blockIdx.y * 32;
  int isbf = *flag;
  const float* shp = sh + (size_t)s0 * 192;
  for (int idx = t; idx < 96 * 64; idx += 256) shs[idx] = shp[idx];
  for (int idx = t; idx < 64 * 64; idx += 256) {
    int v = idx >> 6, d = idx & 63;
    embt[d][v] = emb[(size_t)(v0 + v) * 64 + d];
  }
  __syncthreads();
  int tq = t & 15, tg = t >> 4;
  float acc[2][3][4];
#pragma unroll
  for (int si = 0; si < 2; si++)
#pragma unroll
    for (int k = 0; k < 3; k++)
#pragma unroll
      for (int j = 0; j < 4; j++) acc[si][k][j] = 0.f;
  for (int d = 0; d < 64; d++) {
    float4 ev = *(const float4*)&embt[d][tq * 4];
#pragma unroll
    for (int si = 0; si < 2; si++) {
      int srow = (tg * 2 + si) * 3;
#pragma unroll
      for (int k = 0; k < 3; k++) {
        float a = shs[(srow + k) * 64 + d];
        acc[si][k][0] += a * ev.x;
        acc[si][k][1] += a * ev.y;
        acc[si][k][2] += a * ev.z;
        acc[si][k][3] += a * ev.w;
      }
    }
  }
#pragma unroll
  for (int si = 0; si < 2; si++) {
    float o[4];
#pragma unroll
    for (int j = 0; j < 4; j++)
      o[j] = fmaxf(acc[si][0][j], fmaxf(acc[si][1][j], acc[si][2][j]));
    size_t idx = (size_t)(s0 + tg * 2 + si) * VV + v0 + tq * 4;
    if (isbf) {
      u32_t p0 = (u32_t)f2bf(o[0]) | ((u32_t)f2bf(o[1]) << 16);
      u32_t p1 = (u32_t)f2bf(o[2]) | ((u32_t)f2bf(o[3]) << 16);
      *(uint2*)((us_t*)out + idx) = make_uint2(p0, p1);
    } else {
      *(float4*)((float*)out + idx) = make_float4(o[0], o[1], o[2], o[3]);
    }
  }
}

// ---------------- launcher ----------------
extern "C" void kernel_launch(void* const* d_in, const int* in_sizes, int n_in,
                              void* d_out, int out_size, void* d_ws, size_t ws_size,
                              hipStream_t stream) {
  if (n_in < 21) return;
  const int* x = (const int*)d_in[0];
  const int* ei = (const int*)d_in[1];
  const int* bat = (const int*)d_in[2];

  char* ws = (char*)d_ws;
  size_t off = 0;
  auto A = [&](size_t bytes) -> char* {
    char* p = ws + off;
    off += (bytes + 255) & ~(size_t)255;
    return p;
  };
  int* flag = (int*)A(4);
  float* cv[18];
  for (int i = 0; i < 18; i++) cv[i] = (float*)A((size_t)in_sizes[3 + i] * 4);
  float* e_buf = (float*)A((size_t)NN * 64 * 4);
  float* g_buf = (float*)A((size_t)NN * 4 * 4);
  float* asrc = (float*)A((size_t)NN * 16 * 4);
  float* adst = (float*)A((size_t)NN * 16 * 4);
  us_t* h_pre = (us_t*)A((size_t)NN * 1024 * 2);
  us_t* h1 = (us_t*)A((size_t)NN * 1024 * 2);
  float* h2pre = (float*)A((size_t)NN * 64 * 4);
  float* a2s = (float*)A((size_t)NN * 4);
  float* a2d = (float*)A((size_t)NN * 4);
  float* sess = (float*)A((size_t)NN * 192 * 4);
  float* vq1 = (float*)A((size_t)BB * 192 * 4);
  float* sg = (float*)A((size_t)BB * 192 * 4);
  float* vn = (float*)A((size_t)BB * 192 * 4);
  float* shb = (float*)A((size_t)BB * 192 * 4);
  int* lasti = (int*)A((size_t)BB * 4);
  int* counts = (int*)A((size_t)NN * 4);
  int* offsets = (int*)A((size_t)(NN + 1) * 4);
  int* fillpos = (int*)A((size_t)NN * 4);
  int* adj = (int*)A((size_t)EE * 4);
  if (off > ws_size) return;  // insufficient scratch; fail loudly via wrong output

  hipMemsetAsync(counts, 0, NN * 4, stream);
  hipMemsetAsync(fillpos, 0, NN * 4, stream);
  hipMemsetAsync(sg, 0, BB * 192 * 4, stream);
  hipMemsetAsync(lasti, 0, BB * 4, stream);

  k_detect<<<1, 64, 0, stream>>>(d_in[3], flag);
  for (int i = 0; i < 18; i++) {
    int n = in_sizes[3 + i];
    k_cvt<<<(n + 255) / 256, 256, 0, stream>>>(d_in[3 + i], cv[i], n, flag);
  }
  const float* c_emb = cv[0];
  const float* c_wint = cv[1];
  const float* c_g1W = cv[2];
  const float* c_g1as = cv[3];
  const float* c_g1ad = cv[4];
  const float* c_g1b = cv[5];
  const float* c_g2W = cv[6];
  const float* c_g2as = cv[7];
  const float* c_g2ad = cv[8];
  const float* c_g2b = cv[9];
  const float* c_W1w = cv[10];
  const float* c_W1b = cv[11];
  const float* c_W2w = cv[12];
  const float* c_W2b = cv[13];
  const float* c_qw = cv[14];
  const float* c_qb = cv[15];
  const float* c_W3w = cv[16];
  const float* c_W3b = cv[17];

  k_embed<<<NN * 64 / 256, 256, 0, stream>>>(x, c_emb, c_wint, e_buf, g_buf);
  k_count<<<EE / 256, 256, 0, stream>>>(ei + EE, counts);
  k_scan<<<1, 256, 0, stream>>>(counts, offsets);
  k_fill<<<EE / 256, 256, 0, stream>>>(ei, ei + EE, offsets, fillpos, adj);

  for (int i = 0; i < KI; i++) {
    k_gat1_lin<<<dim3(NN / 64, 8), 256, 0, stream>>>(
        e_buf, g_buf, c_g1W + (size_t)i * 64 * 1024, i, h_pre);
    k_att1<<<NN * 16 * 64 / 256, 256, 0, stream>>>(
        h_pre, c_g1as + i * 1024, c_g1ad + i * 1024, asrc, adst);
    k_gat1_agg<<<NN, 256, 0, stream>>>(
        h_pre, asrc, adst, g_buf, c_g1b + i * 1024, i, offsets, adj, h1);
    k_gat2_lin<<<NN / 16, 256, 0, stream>>>(h1, c_g2W + (size_t)i * 1024 * 64, h2pre);
    k_att2<<<NN * 64 / 256, 256, 0, stream>>>(
        h2pre, c_g2as + i * 64, c_g2ad + i * 64, a2s, a2d);
    k_gat2_agg<<<NN * 64 / 256, 256, 0, stream>>>(
        h2pre, a2s, a2d, g_buf, c_g2b + i * 64, i, offsets, adj, sess);
  }

  k_last<<<NN / 256, 256, 0, stream>>>(bat, lasti);
  k_vq1<<<BB, 192, 0, stream>>>(sess, lasti, c_W1w, c_W1b, vn, vq1);
  k_alpha_sg<<<NN / 8, 192, 0, stream>>>(sess, vq1, bat, c_W2w, c_W2b, c_qw, c_qb, sg);
  k_sh<<<BB, 192, 0, stream>>>(vn, sg, c_W3w, c_W3b, shb);
  k_final<<<dim3(VV / 64, BB / 32), 256, 0, stream>>>(shb, c_emb, d_out, flag);
}

// Round 2
// 445.329 us; speedup vs baseline: 1.9787x; 1.9787x over previous
//
#include <hip/hip_runtime.h>
#include <math.h>

#define NN 16384
#define EE 65536
#define BB 512
#define VV 32000

typedef unsigned short us_t;
typedef unsigned int u32_t;
typedef __attribute__((ext_vector_type(4))) float f32x4;
typedef __attribute__((ext_vector_type(8))) short bf16x8;

__device__ __forceinline__ float bf2f(unsigned int u) {
  return __uint_as_float((u & 0xffffu) << 16);
}
__device__ __forceinline__ unsigned short f2bf(float f) {
  unsigned int x = __float_as_uint(f);
  unsigned int r = (x + 0x7fffu + ((x >> 16) & 1u)) >> 16;
  return (unsigned short)r;
}
__device__ __forceinline__ float wsum(float v) {
#pragma unroll
  for (int o = 32; o; o >>= 1) v += __shfl_xor(v, o, 64);
  return v;
}
__device__ __forceinline__ float redu16(float v) {
  v += __shfl_xor(v, 1, 64);
  v += __shfl_xor(v, 2, 64);
  v += __shfl_xor(v, 4, 64);
  v += __shfl_xor(v, 8, 64);
  return v;
}
__device__ __forceinline__ float lrelu(float x) { return x > 0.f ? x : 0.2f * x; }

// ---------------- dtype probe ----------------
__global__ void k_detect(const void* emb, int* flag) {
  if (threadIdx.x == 0 && blockIdx.x == 0) {
    const us_t* u = (const us_t*)emb;
    int ok = 1;
    for (int i = 0; i < 128; i++) {
      float v = bf2f((unsigned int)u[i]);
      if (!(fabsf(v) <= 0.13f)) { ok = 0; break; }
    }
    *flag = ok;  // 1 => inputs bf16, 0 => f32
  }
}

// ---------------- fused prep: convert + transpose weights ----------------
struct PrepArgs {
  const void* src[17];
  void* dst[17];
  int n[17];
  int kind[17];   // 0 cvt f32, 1 cvt bf16, 2 g1W transpose, 3 g2W transpose
  int start[18];  // block starts; start[17] = total blocks
};

__global__ void k_prep(PrepArgs pa, const int* __restrict__ flag) {
  int blk = blockIdx.x;
  int s = 0;
  while (s < 16 && blk >= pa.start[s + 1]) s++;
  int i = (blk - pa.start[s]) * 256 + threadIdx.x;
  if (i >= pa.n[s]) return;
  float v = (*flag) ? bf2f((unsigned int)((const us_t*)pa.src[s])[i])
                    : ((const float*)pa.src[s])[i];
  int kind = pa.kind[s];
  if (kind == 0) {
    ((float*)pa.dst[s])[i] = v;
  } else if (kind == 1) {
    ((us_t*)pa.dst[s])[i] = f2bf(v);
  } else if (kind == 2) {  // [3][64][1024] -> [3][1024][64]
    int ii = i >> 16, r = i & 65535, k = r >> 10, col = r & 1023;
    ((us_t*)pa.dst[s])[(ii << 16) + col * 64 + k] = f2bf(v);
  } else {  // [3][1024][64] -> [3][64][1024]
    int ii = i >> 16, r = i & 65535, k = r >> 6, col = r & 63;
    ((us_t*)pa.dst[s])[(ii << 16) + col * 1024 + k] = f2bf(v);
  }
}

// ---------------- embedding gather + interest softmax ----------------
__global__ void k_embed(const int* __restrict__ x, const void* __restrict__ embr,
                        const void* __restrict__ wintr, const int* __restrict__ flag,
                        us_t* __restrict__ e_bf, float* __restrict__ g) {
  int gid = blockIdx.x * blockDim.x + threadIdx.x;
  int n = gid >> 6, lane = gid & 63;
  if (n >= NN) return;
  int isbf = *flag;
  size_t ei = (size_t)x[n] * 64 + lane;
  float v = isbf ? bf2f((unsigned int)((const us_t*)embr)[ei]) : ((const float*)embr)[ei];
  e_bf[(size_t)n * 64 + lane] = f2bf(v);
  float w0, w1, w2;
  if (isbf) {
    const us_t* w = (const us_t*)wintr;
    w0 = bf2f(w[lane * 3 + 0]); w1 = bf2f(w[lane * 3 + 1]); w2 = bf2f(w[lane * 3 + 2]);
  } else {
    const float* w = (const float*)wintr;
    w0 = w[lane * 3 + 0]; w1 = w[lane * 3 + 1]; w2 = w[lane * 3 + 2];
  }
  float t0 = wsum(v * w0), t1 = wsum(v * w1), t2 = wsum(v * w2);
  if (lane == 0) {
    float l0 = t0 / 0.1f, l1 = t1 / 0.1f, l2 = t2 / 0.1f;
    float m = fmaxf(l0, fmaxf(l1, l2));
    float p0 = expf(l0 - m), p1 = expf(l1 - m), p2 = expf(l2 - m);
    float inv = 1.0f / (p0 + p1 + p2);
    g[n * 4 + 0] = p0 * inv; g[n * 4 + 1] = p1 * inv;
    g[n * 4 + 2] = p2 * inv; g[n * 4 + 3] = 0.f;
  }
}

// ---------------- CSR build ----------------
__global__ void k_count(const int* __restrict__ dst, int* __restrict__ counts) {
  int e = blockIdx.x * blockDim.x + threadIdx.x;
  if (e < EE) atomicAdd(&counts[dst[e]], 1);
}

__global__ void k_scan(const int* __restrict__ counts, int* __restrict__ offsets) {
  __shared__ int part[256];
  __shared__ int excl[257];
  int t = threadIdx.x;
  int base = t * 64;
  int s = 0;
  for (int j = 0; j < 64; j++) s += counts[base + j];
  part[t] = s;
  __syncthreads();
  if (t == 0) {
    int run = 0;
    for (int j = 0; j < 256; j++) { excl[j] = run; run += part[j]; }
    excl[256] = run;
  }
  __syncthreads();
  int run = excl[t];
  for (int j = 0; j < 64; j++) { offsets[base + j] = run; run += counts[base + j]; }
  if (t == 255) offsets[NN] = excl[256];
}

__global__ void k_fill(const int* __restrict__ src, const int* __restrict__ dst,
                       const int* __restrict__ offsets, int* __restrict__ fillpos,
                       int* __restrict__ adj) {
  int e = blockIdx.x * blockDim.x + threadIdx.x;
  if (e < EE) {
    int d = dst[e];
    int pos = offsets[d] + atomicAdd(&fillpos[d], 1);
    adj[pos] = src[e];
  }
}

// ---------------- GAT1 linear MFMA: e_bf[16384x64] @ Wt -> h_pre bf16 + att dots ----------------
__global__ __launch_bounds__(256) void k_gat1_lin_mfma(
    const us_t* __restrict__ e_bf, const float* __restrict__ g,
    const us_t* __restrict__ Wt, const float* __restrict__ a_s,
    const float* __restrict__ a_d, int intr, us_t* __restrict__ h_pre,
    float* __restrict__ asrc, float* __restrict__ adst) {
  __shared__ uint4 AsU[512];    // 64 rows x 64 k bf16 (swizzled 16B chunks)
  __shared__ uint4 BsU[2048];   // 256 cols x 64 k bf16
  char* As = (char*)AsU;
  char* Bs = (char*)BsU;
  int t = threadIdx.x;
  int col0 = blockIdx.x * 256, row0 = blockIdx.y * 64;
  for (int id = t; id < 512; id += 256) {
    int r = id >> 3, c = id & 7;
    uint4 v = *(const uint4*)&e_bf[(size_t)(row0 + r) * 64 + c * 8];
    *(uint4*)(As + r * 128 + (((c ^ (r & 7))) << 4)) = v;
  }
  for (int id = t; id < 2048; id += 256) {
    int vr = id >> 3, c = id & 7;
    uint4 v = *(const uint4*)&Wt[(size_t)(col0 + vr) * 64 + c * 8];
    *(uint4*)(Bs + vr * 128 + (((c ^ (vr & 7))) << 4)) = v;
  }
  __syncthreads();
  int wv = t >> 6, lane = t & 63, li = lane & 15, lq = lane >> 4;
  int head = blockIdx.x * 4 + wv;
  f32x4 acc[4][4];
#pragma unroll
  for (int rb = 0; rb < 4; rb++)
#pragma unroll
    for (int sub = 0; sub < 4; sub++) acc[rb][sub] = 0;
#pragma unroll
  for (int ks = 0; ks < 2; ks++) {
    bf16x8 bfr[4];
#pragma unroll
    for (int sub = 0; sub < 4; sub++) {
      int vr = wv * 64 + sub * 16 + li;
      bfr[sub] = *(const bf16x8*)(Bs + vr * 128 + ((((ks << 2) | lq) ^ (vr & 7)) << 4));
    }
#pragma unroll
    for (int rb = 0; rb < 4; rb++) {
      int r = rb * 16 + li;
      bf16x8 af = *(const bf16x8*)(As + r * 128 + ((((ks << 2) | lq) ^ (r & 7)) << 4));
#pragma unroll
      for (int sub = 0; sub < 4; sub++)
        acc[rb][sub] = __builtin_amdgcn_mfma_f32_16x16x32_bf16(af, bfr[sub], acc[rb][sub], 0, 0, 0);
    }
  }
  float asv[4], adv[4];
#pragma unroll
  for (int sub = 0; sub < 4; sub++) {
    asv[sub] = a_s[head * 64 + sub * 16 + li];
    adv[sub] = a_d[head * 64 + sub * 16 + li];
  }
#pragma unroll
  for (int rb = 0; rb < 4; rb++) {
#pragma unroll
    for (int rr = 0; rr < 4; rr++) {
      int n = row0 + rb * 16 + lq * 4 + rr;
      float gv = g[n * 4 + intr];
      float s = 0.f, d = 0.f;
#pragma unroll
      for (int sub = 0; sub < 4; sub++) {
        float hv = acc[rb][sub][rr] * gv;
        s += hv * asv[sub];
        d += hv * adv[sub];
        h_pre[(size_t)n * 1024 + head * 64 + sub * 16 + li] = f2bf(hv);
      }
      s = redu16(s); d = redu16(d);
      if (li == 0) { asrc[n * 16 + head] = s; adst[n * 16 + head] = d; }
    }
  }
}

__device__ __forceinline__ void ld_bf4(const us_t* p, float* f) {
  uint2 u = *(const uint2*)p;
  f[0] = bf2f(u.x); f[1] = bf2f(u.x >> 16);
  f[2] = bf2f(u.y); f[3] = bf2f(u.y >> 16);
}

// ---------------- GAT1 edge-softmax aggregation ----------------
__global__ __launch_bounds__(256) void k_gat1_agg(
    const us_t* __restrict__ h_pre,
    const float* __restrict__ asrc, const float* __restrict__ adst,
    const float* __restrict__ g, const float* __restrict__ bias, int intr,
    const int* __restrict__ offsets, const int* __restrict__ adj,
    us_t* __restrict__ h1) {
  __shared__ float m_s[16], den_s[16], ad_s[16];
  int n = blockIdx.x;
  int t = threadIdx.x;
  bool nvalid = g[n * 4 + intr] > (1.0f / 3.0f);
  int beg = offsets[n], end = offsets[n + 1];
  if (t < 16) {
    int head = t;
    float ad = adst[n * 16 + head];
    float l = lrelu(asrc[n * 16 + head] + ad);
    float m = l;
    if (nvalid) {
      for (int j = beg; j < end; j++) {
        int s = adj[j];
        if (g[s * 4 + intr] > (1.0f / 3.0f))
          m = fmaxf(m, lrelu(asrc[s * 16 + head] + ad));
      }
    }
    float den = expf(l - m);
    if (nvalid) {
      for (int j = beg; j < end; j++) {
        int s = adj[j];
        if (g[s * 4 + intr] > (1.0f / 3.0f))
          den += expf(lrelu(asrc[s * 16 + head] + ad) - m);
      }
    }
    m_s[head] = m; den_s[head] = den; ad_s[head] = ad;
  }
  __syncthreads();
  int head = t >> 4, d0 = (t & 15) * 4;
  float m = m_s[head], ad = ad_s[head];
  float acc[4], hv[4];
  {
    float p = expf(lrelu(asrc[n * 16 + head] + ad) - m);
    ld_bf4(&h_pre[(size_t)n * 1024 + head * 64 + d0], hv);
#pragma unroll
    for (int q = 0; q < 4; q++) acc[q] = p * hv[q];
  }
  if (nvalid) {
    for (int j = beg; j < end; j++) {
      int s = adj[j];
      if (g[s * 4 + intr] > (1.0f / 3.0f)) {
        float p = expf(lrelu(asrc[s * 16 + head] + ad) - m);
        ld_bf4(&h_pre[(size_t)s * 1024 + head * 64 + d0], hv);
#pragma unroll
        for (int q = 0; q < 4; q++) acc[q] += p * hv[q];
      }
    }
  }
  float inv = 1.0f / den_s[head];
  float v0 = fmaxf(acc[0] * inv + bias[head * 64 + d0 + 0], 0.f);
  float v1 = fmaxf(acc[1] * inv + bias[head * 64 + d0 + 1], 0.f);
  float v2 = fmaxf(acc[2] * inv + bias[head * 64 + d0 + 2], 0.f);
  float v3 = fmaxf(acc[3] * inv + bias[head * 64 + d0 + 3], 0.f);
  u32_t o0 = (u32_t)f2bf(v0) | ((u32_t)f2bf(v1) << 16);
  u32_t o1 = (u32_t)f2bf(v2) | ((u32_t)f2bf(v3) << 16);
  *(uint2*)&h1[(size_t)n * 1024 + head * 64 + d0] = make_uint2(o0, o1);
}

// ---------------- GAT2 linear MFMA: h1[16384x1024] @ Wt[64x1024] -> h2pre f32 + att dots ----------------
__global__ __launch_bounds__(256) void k_gat2_lin_mfma(
    const us_t* __restrict__ h1, const us_t* __restrict__ Wt,
    const float* __restrict__ a_s, const float* __restrict__ a_d,
    float* __restrict__ h2pre, float* __restrict__ a2s, float* __restrict__ a2d) {
  __shared__ uint4 AsU[1024];  // 64 rows x 128 k
  __shared__ uint4 BsU[1024];  // 64 cols x 128 k
  char* As = (char*)AsU;
  char* Bs = (char*)BsU;
  int t = threadIdx.x;
  int row0 = blockIdx.x * 64;
  int wv = t >> 6, lane = t & 63, li = lane & 15, lq = lane >> 4;
  f32x4 acc[4];
#pragma unroll
  for (int sub = 0; sub < 4; sub++) acc[sub] = 0;
  for (int kb = 0; kb < 8; kb++) {
    __syncthreads();
    for (int id = t; id < 1024; id += 256) {
      int r = id >> 4, c = id & 15;
      uint4 v = *(const uint4*)&h1[(size_t)(row0 + r) * 1024 + kb * 128 + c * 8];
      *(uint4*)(As + r * 256 + ((c ^ (r & 15)) << 4)) = v;
      uint4 w = *(const uint4*)&Wt[(size_t)r * 1024 + kb * 128 + c * 8];
      *(uint4*)(Bs + r * 256 + ((c ^ (r & 15)) << 4)) = w;
    }
    __syncthreads();
#pragma unroll
    for (int ks = 0; ks < 4; ks++) {
      int r = wv * 16 + li;
      bf16x8 af = *(const bf16x8*)(As + r * 256 + ((((ks << 2) | lq) ^ (r & 15)) << 4));
#pragma unroll
      for (int sub = 0; sub < 4; sub++) {
        int vr = sub * 16 + li;
        bf16x8 bf_ = *(const bf16x8*)(Bs + vr * 256 + ((((ks << 2) | lq) ^ (vr & 15)) << 4));
        acc[sub] = __builtin_amdgcn_mfma_f32_16x16x32_bf16(af, bf_, acc[sub], 0, 0, 0);
      }
    }
  }
  float asv[4], adv[4];
#pragma unroll
  for (int sub = 0; sub < 4; sub++) {
    asv[sub] = a_s[sub * 16 + li];
    adv[sub] = a_d[sub * 16 + li];
  }
#pragma unroll
  for (int rr = 0; rr < 4; rr++) {
    int n = row0 + wv * 16 + lq * 4 + rr;
    float s = 0.f, d = 0.f;
#pragma unroll
    for (int sub = 0; sub < 4; sub++) {
      float hv = acc[sub][rr];
      h2pre[(size_t)n * 64 + sub * 16 + li] = hv;
      s += hv * asv[sub];
      d += hv * adv[sub];
    }
    s = redu16(s); d = redu16(d);
    if (li == 0) { a2s[n] = s; a2d[n] = d; }
  }
}

// ---------------- GAT2 aggregation -> sess ----------------
__global__ void k_gat2_agg(const float* __restrict__ h2pre,
                           const float* __restrict__ a2s, const float* __restrict__ a2d,
                           const float* __restrict__ g, const float* __restrict__ b2,
                           int intr, const int* __restrict__ offsets,
                           const int* __restrict__ adj, float* __restrict__ sess) {
  int gid = blockIdx.x * blockDim.x + threadIdx.x;
  int n = gid >> 6, lane = gid & 63;
  if (n >= NN) return;
  bool nvalid = g[n * 4 + intr] > (1.0f / 3.0f);
  float ad = a2d[n];
  float ls = lrelu(a2s[n] + ad);
  float m = ls;
  int beg = offsets[n], end = offsets[n + 1];
  if (nvalid) {
    for (int j = beg; j < end; j++) {
      int s = adj[j];
      if (g[s * 4 + intr] > (1.0f / 3.0f)) m = fmaxf(m, lrelu(a2s[s] + ad));
    }
  }
  float p = expf(ls - m);
  float den = p;
  float acc = p * h2pre[(size_t)n * 64 + lane];
  if (nvalid) {
    for (int j = beg; j < end; j++) {
      int s = adj[j];
      if (g[s * 4 + intr] > (1.0f / 3.0f)) {
        float w2 = expf(lrelu(a2s[s] + ad) - m);
        den += w2;
        acc += w2 * h2pre[(size_t)s * 64 + lane];
      }
    }
  }
  sess[(size_t)n * 192 + intr * 64 + lane] = acc / den + b2[lane];
}

// ---------------- scoring ----------------
__global__ void k_last(const int* __restrict__ batch, int* __restrict__ lasti) {
  int n = blockIdx.x * blockDim.x + threadIdx.x;
  if (n < NN) atomicMax(&lasti[batch[n]], n);
}

__global__ __launch_bounds__(192) void k_vq1(
    const float* __restrict__ sess, const int* __restrict__ lasti,
    const float* __restrict__ W1w, const float* __restrict__ W1b,
    float* __restrict__ vn, float* __restrict__ vq1) {
  __shared__ float row[192];
  int b = blockIdx.x, j = threadIdx.x;
  int li = lasti[b];
  float v = sess[(size_t)li * 192 + j];
  row[j] = v;
  vn[b * 192 + j] = v;
  __syncthreads();
  float acc = W1b[j];
  for (int k = 0; k < 192; k++) acc += row[k] * W1w[k * 192 + j];
  vq1[b * 192 + j] = acc;
}

__global__ __launch_bounds__(192) void k_alpha_sg(
    const float* __restrict__ sess, const float* __restrict__ vq1,
    const int* __restrict__ batch, const float* __restrict__ W2w,
    const float* __restrict__ W2b, const float* __restrict__ qw,
    const float* __restrict__ qb, float* __restrict__ sg) {
  __shared__ float srow[8][192];
  __shared__ float red[192];
  __shared__ float alpha_sh;
  int t = threadIdx.x;
  int n0 = blockIdx.x * 8;
#pragma unroll
  for (int q = 0; q < 8; q++) srow[q][t] = sess[(size_t)(n0 + q) * 192 + t];
  __syncthreads();
  float q2[8];
#pragma unroll
  for (int q = 0; q < 8; q++) q2[q] = W2b[t];
  for (int k = 0; k < 192; k++) {
    float wv = W2w[k * 192 + t];
#pragma unroll
    for (int q = 0; q < 8; q++) q2[q] += srow[q][k] * wv;
  }
  float qwt = qw[t];
  for (int q = 0; q < 8; q++) {
    int n = n0 + q;
    int bq = batch[n];
    float s = 1.0f / (1.0f + expf(-(vq1[bq * 192 + t] + q2[q])));
    red[t] = s * qwt;
    __syncthreads();
    if (t < 64) {
      float r = red[t] + red[t + 64] + red[t + 128];
#pragma unroll
      for (int o = 32; o; o >>= 1) r += __shfl_xor(r, o, 64);
      if (t == 0) alpha_sh = r + qb[0];
    }
    __syncthreads();
    float alpha = alpha_sh;
    atomicAdd(&sg[bq * 192 + t], alpha * srow[q][t]);
    __syncthreads();
  }
}

__global__ __launch_bounds__(192) void k_sh(
    const float* __restrict__ vn, const float* __restrict__ sg,
    const float* __restrict__ W3w, const float* __restrict__ W3b,
    float* __restrict__ sh) {
  __shared__ float row[384];
  int b = blockIdx.x, j = threadIdx.x;
  row[j] = vn[b * 192 + j];
  row[192 + j] = sg[b * 192 + j];
  __syncthreads();
  float acc = W3b[j];
  for (int k = 0; k < 384; k++) acc += row[k] * W3w[k * 192 + j];
  sh[b * 192 + j] = acc;
}

// ---------------- final MFMA: sh(bf16) @ emb_bf^T, max over 3 interests ----------------
__global__ __launch_bounds__(256) void k_final_mfma(
    const float* __restrict__ sh, const us_t* __restrict__ emb_bf,
    void* __restrict__ out, const int* __restrict__ flag) {
  __shared__ uint4 AsU[384];    // 3 x 16 rows x 64 k bf16
  __shared__ uint4 BsU[2048];   // 256 v x 64 d bf16
  char* As = (char*)AsU;
  char* Bs = (char*)BsU;
  int t = threadIdx.x;
  int v0 = blockIdx.x * 256, b0 = blockIdx.y * 16;
  for (int id = t; id < 384; id += 256) {
    int i2 = id >> 7, rem = id & 127, r = rem >> 3, c = rem & 7;
    const float* p = &sh[(size_t)(b0 + r) * 192 + i2 * 64 + c * 8];
    float4 f0 = *(const float4*)p;
    float4 f1 = *(const float4*)(p + 4);
    u32_t w0 = (u32_t)f2bf(f0.x) | ((u32_t)f2bf(f0.y) << 16);
    u32_t w1 = (u32_t)f2bf(f0.z) | ((u32_t)f2bf(f0.w) << 16);
    u32_t w2 = (u32_t)f2bf(f1.x) | ((u32_t)f2bf(f1.y) << 16);
    u32_t w3 = (u32_t)f2bf(f1.z) | ((u32_t)f2bf(f1.w) << 16);
    *(uint4*)(As + i2 * 2048 + r * 128 + ((c ^ (r & 7)) << 4)) = make_uint4(w0, w1, w2, w3);
  }
  for (int id = t; id < 2048; id += 256) {
    int vr = id >> 3, c = id & 7;
    uint4 v = *(const uint4*)&emb_bf[(size_t)(v0 + vr) * 64 + c * 8];
    *(uint4*)(Bs + vr * 128 + ((c ^ (vr & 7)) << 4)) = v;
  }
  __syncthreads();
  int wv = t >> 6, lane = t & 63, li = lane & 15, lq = lane >> 4;
  int cb = wv * 64;
  int isbf = *flag;
  f32x4 acc[3][4];
#pragma unroll
  for (int i = 0; i < 3; i++)
#pragma unroll
    for (int sub = 0; sub < 4; sub++) acc[i][sub] = 0;
#pragma unroll
  for (int ks = 0; ks < 2; ks++) {
    bf16x8 bfr[4];
#pragma unroll
    for (int sub = 0; sub < 4; sub++) {
      int vr = cb + sub * 16 + li;
      bfr[sub] = *(const bf16x8*)(Bs + vr * 128 + ((((ks << 2) | lq) ^ (vr & 7)) << 4));
    }
#pragma unroll
    for (int i = 0; i < 3; i++) {
      bf16x8 af = *(const bf16x8*)(As + i * 2048 + li * 128 + ((((ks << 2) | lq) ^ (li & 7)) << 4));
#pragma unroll
      for (int sub = 0; sub < 4; sub++)
        acc[i][sub] = __builtin_amdgcn_mfma_f32_16x16x32_bf16(af, bfr[sub], acc[i][sub], 0, 0, 0);
    }
  }
#pragma unroll
  for (int sub = 0; sub < 4; sub++) {
    int col = v0 + cb + sub * 16 + li;
#pragma unroll
    for (int rr = 0; rr < 4; rr++) {
      float o = fmaxf(fmaxf(acc[0][sub][rr], acc[1][sub][rr]), acc[2][sub][rr]);
      int b = b0 + lq * 4 + rr;
      if (isbf) ((us_t*)out)[(size_t)b * VV + col] = f2bf(o);
      else ((float*)out)[(size_t)b * VV + col] = o;
    }
  }
}

// ---------------- launcher ----------------
extern "C" void kernel_launch(void* const* d_in, const int* in_sizes, int n_in,
                              void* d_out, int out_size, void* d_ws, size_t ws_size,
                              hipStream_t stream) {
  if (n_in < 21) return;
  const int* x = (const int*)d_in[0];
  const int* ei = (const int*)d_in[1];
  const int* bat = (const int*)d_in[2];

  char* ws = (char*)d_ws;
  size_t off = 0;
  auto A = [&](size_t bytes) -> char* {
    char* p = ws + off;
    off += (bytes + 255) & ~(size_t)255;
    return p;
  };
  int* flag = (int*)A(4);
  us_t* emb_bf = (us_t*)A((size_t)VV * 64 * 2);
  us_t* e_bf = (us_t*)A((size_t)NN * 64 * 2);
  us_t* g1Wt = (us_t*)A((size_t)3 * 65536 * 2);
  us_t* g2Wt = (us_t*)A((size_t)3 * 65536 * 2);
  float* c_g1as = (float*)A(3072 * 4);
  float* c_g1ad = (float*)A(3072 * 4);
  float* c_g1b = (float*)A(3072 * 4);
  float* c_g2as = (float*)A(192 * 4);
  float* c_g2ad = (float*)A(192 * 4);
  float* c_g2b = (float*)A(192 * 4);
  float* c_W1w = (float*)A(36864 * 4);
  float* c_W1b = (float*)A(192 * 4);
  float* c_W2w = (float*)A(36864 * 4);
  float* c_W2b = (float*)A(192 * 4);
  float* c_qw = (float*)A(192 * 4);
  float* c_qb = (float*)A(4);
  float* c_W3w = (float*)A(73728 * 4);
  float* c_W3b = (float*)A(192 * 4);
  float* g_buf = (float*)A((size_t)NN * 4 * 4);
  float* asrc = (float*)A((size_t)NN * 16 * 4);
  float* adst = (float*)A((size_t)NN * 16 * 4);
  us_t* h_pre = (us_t*)A((size_t)NN * 1024 * 2);
  us_t* h1 = (us_t*)A((size_t)NN * 1024 * 2);
  float* h2pre = (float*)A((size_t)NN * 64 * 4);
  float* a2s = (float*)A((size_t)NN * 4);
  float* a2d = (float*)A((size_t)NN * 4);
  float* sess = (float*)A((size_t)NN * 192 * 4);
  float* vq1 = (float*)A((size_t)BB * 192 * 4);
  float* sg = (float*)A((size_t)BB * 192 * 4);
  float* vn = (float*)A((size_t)BB * 192 * 4);
  float* shb = (float*)A((size_t)BB * 192 * 4);
  int* lasti = (int*)A((size_t)BB * 4);
  int* counts = (int*)A((size_t)NN * 4);
  int* offsets = (int*)A((size_t)(NN + 1) * 4);
  int* fillpos = (int*)A((size_t)NN * 4);
  int* adj = (int*)A((size_t)EE * 4);
  if (off > ws_size) return;

  hipMemsetAsync(counts, 0, NN * 4, stream);
  hipMemsetAsync(fillpos, 0, NN * 4, stream);
  hipMemsetAsync(sg, 0, BB * 192 * 4, stream);
  hipMemsetAsync(lasti, 0, BB * 4, stream);

  k_detect<<<1, 64, 0, stream>>>(d_in[3], flag);

  PrepArgs pa;
  int nb = 0, idx = 0;
  auto SEC = [&](const void* s, void* d, int n, int kind) {
    pa.src[idx] = s; pa.dst[idx] = d; pa.n[idx] = n; pa.kind[idx] = kind;
    pa.start[idx] = nb; nb += (n + 255) / 256; idx++;
  };
  SEC(d_in[3], emb_bf, VV * 64, 1);
  SEC(d_in[5], g1Wt, 196608, 2);
  SEC(d_in[9], g2Wt, 196608, 3);
  SEC(d_in[6], c_g1as, 3072, 0);
  SEC(d_in[7], c_g1ad, 3072, 0);
  SEC(d_in[8], c_g1b, 3072, 0);
  SEC(d_in[10], c_g2as, 192, 0);
  SEC(d_in[11], c_g2ad, 192, 0);
  SEC(d_in[12], c_g2b, 192, 0);
  SEC(d_in[13], c_W1w, 36864, 0);
  SEC(d_in[14], c_W1b, 192, 0);
  SEC(d_in[15], c_W2w, 36864, 0);
  SEC(d_in[16], c_W2b, 192, 0);
  SEC(d_in[17], c_qw, 192, 0);
  SEC(d_in[18], c_qb, 1, 0);
  SEC(d_in[19], c_W3w, 73728, 0);
  SEC(d_in[20], c_W3b, 192, 0);
  pa.start[17] = nb;
  k_prep<<<nb, 256, 0, stream>>>(pa, flag);

  k_embed<<<NN * 64 / 256, 256, 0, stream>>>(x, d_in[3], d_in[4], flag, e_bf, g_buf);
  k_count<<<EE / 256, 256, 0, stream>>>(ei + EE, counts);
  k_scan<<<1, 256, 0, stream>>>(counts, offsets);
  k_fill<<<EE / 256, 256, 0, stream>>>(ei, ei + EE, offsets, fillpos, adj);

  for (int i = 0; i < 3; i++) {
    k_gat1_lin_mfma<<<dim3(4, NN / 64), 256, 0, stream>>>(
        e_bf, g_buf, g1Wt + (size_t)i * 65536, c_g1as + i * 1024, c_g1ad + i * 1024,
        i, h_pre, asrc, adst);
    k_gat1_agg<<<NN, 256, 0, stream>>>(
        h_pre, asrc, adst, g_buf, c_g1b + i * 1024, i, offsets, adj, h1);
    k_gat2_lin_mfma<<<NN / 64, 256, 0, stream>>>(
        h1, g2Wt + (size_t)i * 65536, c_g2as + i * 64, c_g2ad + i * 64,
        h2pre, a2s, a2d);
    k_gat2_agg<<<NN * 64 / 256, 256, 0, stream>>>(
        h2pre, a2s, a2d, g_buf, c_g2b + i * 64, i, offsets, adj, sess);
  }

  k_last<<<NN / 256, 256, 0, stream>>>(bat, lasti);
  k_vq1<<<BB, 192, 0, stream>>>(sess, lasti, c_W1w, c_W1b, vn, vq1);
  k_alpha_sg<<<NN / 8, 192, 0, stream>>>(sess, vq1, bat, c_W2w, c_W2b, c_qw, c_qb, sg);
  k_sh<<<BB, 192, 0, stream>>>(vn, sg, c_W3w, c_W3b, shb);
  k_final_mfma<<<dim3(VV / 256, BB / 16), 256, 0, stream>>>(shb, emb_bf, d_out, flag);
}

// Round 3
// 360.026 us; speedup vs baseline: 2.4475x; 1.2369x over previous
//
#include <hip/hip_runtime.h>
#include <math.h>

#define NN 16384
#define EE 65536
#define BB 512
#define VV 32000

typedef unsigned short us_t;
typedef unsigned int u32_t;
typedef __attribute__((ext_vector_type(4))) float f32x4;
typedef __attribute__((ext_vector_type(8))) short bf16x8;

__device__ __forceinline__ float bf2f(unsigned int u) {
  return __uint_as_float((u & 0xffffu) << 16);
}
__device__ __forceinline__ unsigned short f2bf(float f) {
  unsigned int x = __float_as_uint(f);
  unsigned int r = (x + 0x7fffu + ((x >> 16) & 1u)) >> 16;
  return (unsigned short)r;
}
__device__ __forceinline__ float wsum(float v) {
#pragma unroll
  for (int o = 32; o; o >>= 1) v += __shfl_xor(v, o, 64);
  return v;
}
__device__ __forceinline__ float redu16(float v) {
  v += __shfl_xor(v, 1, 64);
  v += __shfl_xor(v, 2, 64);
  v += __shfl_xor(v, 4, 64);
  v += __shfl_xor(v, 8, 64);
  return v;
}
__device__ __forceinline__ float lrelu(float x) { return x > 0.f ? x : 0.2f * x; }

// ---------------- dtype probe ----------------
__global__ void k_detect(const void* emb, int* flag) {
  if (threadIdx.x == 0 && blockIdx.x == 0) {
    const us_t* u = (const us_t*)emb;
    int ok = 1;
    for (int i = 0; i < 128; i++) {
      float v = bf2f((unsigned int)u[i]);
      if (!(fabsf(v) <= 0.13f)) { ok = 0; break; }
    }
    *flag = ok;  // 1 => inputs bf16, 0 => f32
  }
}

// ---------------- fused prep: convert + transpose weights ----------------
struct PrepArgs {
  const void* src[17];
  void* dst[17];
  int n[17];
  int kind[17];   // 0 cvt f32, 1 cvt bf16, 2 g1W T, 3 g2W T, 4 W2 T (192x192)
  int start[18];
};

__global__ void k_prep(PrepArgs pa, const int* __restrict__ flag) {
  int blk = blockIdx.x;
  int s = 0;
  while (s < 16 && blk >= pa.start[s + 1]) s++;
  int i = (blk - pa.start[s]) * 256 + threadIdx.x;
  if (i >= pa.n[s]) return;
  float v = (*flag) ? bf2f((unsigned int)((const us_t*)pa.src[s])[i])
                    : ((const float*)pa.src[s])[i];
  int kind = pa.kind[s];
  if (kind == 0) {
    ((float*)pa.dst[s])[i] = v;
  } else if (kind == 1) {
    ((us_t*)pa.dst[s])[i] = f2bf(v);
  } else if (kind == 2) {  // [3][64][1024] -> [3][1024][64]
    int ii = i >> 16, r = i & 65535, k = r >> 10, col = r & 1023;
    ((us_t*)pa.dst[s])[(ii << 16) + col * 64 + k] = f2bf(v);
  } else if (kind == 3) {  // [3][1024][64] -> [3][64][1024]
    int ii = i >> 16, r = i & 65535, k = r >> 6, col = r & 63;
    ((us_t*)pa.dst[s])[(ii << 16) + col * 1024 + k] = f2bf(v);
  } else {  // [192][192] -> [192][192]^T
    int k = i / 192, col = i % 192;
    ((us_t*)pa.dst[s])[col * 192 + k] = f2bf(v);
  }
}

// ---------------- embedding gather + interest softmax ----------------
__global__ void k_embed(const int* __restrict__ x, const void* __restrict__ embr,
                        const void* __restrict__ wintr, const int* __restrict__ flag,
                        us_t* __restrict__ e_bf, float* __restrict__ g) {
  int gid = blockIdx.x * blockDim.x + threadIdx.x;
  int n = gid >> 6, lane = gid & 63;
  if (n >= NN) return;
  int isbf = *flag;
  size_t ei = (size_t)x[n] * 64 + lane;
  float v = isbf ? bf2f((unsigned int)((const us_t*)embr)[ei]) : ((const float*)embr)[ei];
  e_bf[(size_t)n * 64 + lane] = f2bf(v);
  float w0, w1, w2;
  if (isbf) {
    const us_t* w = (const us_t*)wintr;
    w0 = bf2f(w[lane * 3 + 0]); w1 = bf2f(w[lane * 3 + 1]); w2 = bf2f(w[lane * 3 + 2]);
  } else {
    const float* w = (const float*)wintr;
    w0 = w[lane * 3 + 0]; w1 = w[lane * 3 + 1]; w2 = w[lane * 3 + 2];
  }
  float t0 = wsum(v * w0), t1 = wsum(v * w1), t2 = wsum(v * w2);
  if (lane == 0) {
    float l0 = t0 / 0.1f, l1 = t1 / 0.1f, l2 = t2 / 0.1f;
    float m = fmaxf(l0, fmaxf(l1, l2));
    float p0 = __expf(l0 - m), p1 = __expf(l1 - m), p2 = __expf(l2 - m);
    float inv = 1.0f / (p0 + p1 + p2);
    g[n * 4 + 0] = p0 * inv; g[n * 4 + 1] = p1 * inv;
    g[n * 4 + 2] = p2 * inv; g[n * 4 + 3] = 0.f;
  }
}

// ---------------- CSR build ----------------
__global__ void k_count(const int* __restrict__ dst, int* __restrict__ counts) {
  int e = blockIdx.x * blockDim.x + threadIdx.x;
  if (e < EE) atomicAdd(&counts[dst[e]], 1);
}

__global__ void k_scan(const int* __restrict__ counts, int* __restrict__ offsets) {
  __shared__ int part[256];
  __shared__ int excl[257];
  int t = threadIdx.x;
  int base = t * 64;
  int s = 0;
  for (int j = 0; j < 64; j++) s += counts[base + j];
  part[t] = s;
  __syncthreads();
  if (t == 0) {
    int run = 0;
    for (int j = 0; j < 256; j++) { excl[j] = run; run += part[j]; }
    excl[256] = run;
  }
  __syncthreads();
  int run = excl[t];
  for (int j = 0; j < 64; j++) { offsets[base + j] = run; run += counts[base + j]; }
  if (t == 255) offsets[NN] = excl[256];
}

__global__ void k_fill(const int* __restrict__ src, const int* __restrict__ dst,
                       const int* __restrict__ offsets, int* __restrict__ fillpos,
                       int* __restrict__ adj) {
  int e = blockIdx.x * blockDim.x + threadIdx.x;
  if (e < EE) {
    int d = dst[e];
    int pos = offsets[d] + atomicAdd(&fillpos[d], 1);
    adj[pos] = src[e];
  }
}

// ---------------- GAT1 linear MFMA + att dots ----------------
__global__ __launch_bounds__(256) void k_gat1_lin_mfma(
    const us_t* __restrict__ e_bf, const float* __restrict__ g,
    const us_t* __restrict__ Wt, const float* __restrict__ a_s,
    const float* __restrict__ a_d, int intr, us_t* __restrict__ h_pre,
    float* __restrict__ asrc, float* __restrict__ adst) {
  __shared__ uint4 AsU[512];
  __shared__ uint4 BsU[2048];
  char* As = (char*)AsU;
  char* Bs = (char*)BsU;
  int t = threadIdx.x;
  int col0 = blockIdx.x * 256, row0 = blockIdx.y * 64;
  for (int id = t; id < 512; id += 256) {
    int r = id >> 3, c = id & 7;
    uint4 v = *(const uint4*)&e_bf[(size_t)(row0 + r) * 64 + c * 8];
    *(uint4*)(As + r * 128 + (((c ^ (r & 7))) << 4)) = v;
  }
  for (int id = t; id < 2048; id += 256) {
    int vr = id >> 3, c = id & 7;
    uint4 v = *(const uint4*)&Wt[(size_t)(col0 + vr) * 64 + c * 8];
    *(uint4*)(Bs + vr * 128 + (((c ^ (vr & 7))) << 4)) = v;
  }
  __syncthreads();
  int wv = t >> 6, lane = t & 63, li = lane & 15, lq = lane >> 4;
  int head = blockIdx.x * 4 + wv;
  f32x4 acc[4][4];
#pragma unroll
  for (int rb = 0; rb < 4; rb++)
#pragma unroll
    for (int sub = 0; sub < 4; sub++) acc[rb][sub] = 0;
#pragma unroll
  for (int ks = 0; ks < 2; ks++) {
    bf16x8 bfr[4];
#pragma unroll
    for (int sub = 0; sub < 4; sub++) {
      int vr = wv * 64 + sub * 16 + li;
      bfr[sub] = *(const bf16x8*)(Bs + vr * 128 + ((((ks << 2) | lq) ^ (vr & 7)) << 4));
    }
#pragma unroll
    for (int rb = 0; rb < 4; rb++) {
      int r = rb * 16 + li;
      bf16x8 af = *(const bf16x8*)(As + r * 128 + ((((ks << 2) | lq) ^ (r & 7)) << 4));
#pragma unroll
      for (int sub = 0; sub < 4; sub++)
        acc[rb][sub] = __builtin_amdgcn_mfma_f32_16x16x32_bf16(af, bfr[sub], acc[rb][sub], 0, 0, 0);
    }
  }
  float asv[4], adv[4];
#pragma unroll
  for (int sub = 0; sub < 4; sub++) {
    asv[sub] = a_s[head * 64 + sub * 16 + li];
    adv[sub] = a_d[head * 64 + sub * 16 + li];
  }
#pragma unroll
  for (int rb = 0; rb < 4; rb++) {
#pragma unroll
    for (int rr = 0; rr < 4; rr++) {
      int n = row0 + rb * 16 + lq * 4 + rr;
      float gv = g[n * 4 + intr];
      float s = 0.f, d = 0.f;
#pragma unroll
      for (int sub = 0; sub < 4; sub++) {
        float hv = acc[rb][sub][rr] * gv;
        s += hv * asv[sub];
        d += hv * adv[sub];
        h_pre[(size_t)n * 1024 + head * 64 + sub * 16 + li] = f2bf(hv);
      }
      s = redu16(s); d = redu16(d);
      if (li == 0) { asrc[n * 16 + head] = s; adst[n * 16 + head] = d; }
    }
  }
}

// ---------------- GAT1 aggregation: wave-per-node, online softmax ----------------
__global__ __launch_bounds__(256) void k_gat1_agg2(
    const us_t* __restrict__ h_pre, const float* __restrict__ asrc,
    const float* __restrict__ adst, const float* __restrict__ g,
    const float* __restrict__ bias, int intr,
    const int* __restrict__ offsets, const int* __restrict__ adj,
    us_t* __restrict__ h1) {
  int t = threadIdx.x;
  int wv = t >> 6, lane = t & 63;
  int n = blockIdx.x * 4 + wv;
  int head = lane >> 2;
  const float thr = 1.0f / 3.0f;
  float ad = adst[n * 16 + head];
  float m = lrelu(asrc[n * 16 + head] + ad);
  float den = 1.f;
  float acc[16];
  {
    const uint4* hp = (const uint4*)&h_pre[(size_t)n * 1024 + lane * 16];
    uint4 a = hp[0], b = hp[1];
    acc[0] = bf2f(a.x); acc[1] = bf2f(a.x >> 16);
    acc[2] = bf2f(a.y); acc[3] = bf2f(a.y >> 16);
    acc[4] = bf2f(a.z); acc[5] = bf2f(a.z >> 16);
    acc[6] = bf2f(a.w); acc[7] = bf2f(a.w >> 16);
    acc[8] = bf2f(b.x); acc[9] = bf2f(b.x >> 16);
    acc[10] = bf2f(b.y); acc[11] = bf2f(b.y >> 16);
    acc[12] = bf2f(b.z); acc[13] = bf2f(b.z >> 16);
    acc[14] = bf2f(b.w); acc[15] = bf2f(b.w >> 16);
  }
  if (g[n * 4 + intr] > thr) {
    int beg = offsets[n], end = offsets[n + 1];
    for (int j = beg; j < end; j++) {
      int s = adj[j];
      if (g[s * 4 + intr] > thr) {
        float l = lrelu(asrc[s * 16 + head] + ad);
        if (l > m) {
          float sc = __expf(m - l);
          den *= sc;
#pragma unroll
          for (int k = 0; k < 16; k++) acc[k] *= sc;
          m = l;
        }
        float p = __expf(l - m);
        den += p;
        const uint4* hp = (const uint4*)&h_pre[(size_t)s * 1024 + lane * 16];
        uint4 a = hp[0], b = hp[1];
        acc[0] += p * bf2f(a.x); acc[1] += p * bf2f(a.x >> 16);
        acc[2] += p * bf2f(a.y); acc[3] += p * bf2f(a.y >> 16);
        acc[4] += p * bf2f(a.z); acc[5] += p * bf2f(a.z >> 16);
        acc[6] += p * bf2f(a.w); acc[7] += p * bf2f(a.w >> 16);
        acc[8] += p * bf2f(b.x); acc[9] += p * bf2f(b.x >> 16);
        acc[10] += p * bf2f(b.y); acc[11] += p * bf2f(b.y >> 16);
        acc[12] += p * bf2f(b.z); acc[13] += p * bf2f(b.z >> 16);
        acc[14] += p * bf2f(b.w); acc[15] += p * bf2f(b.w >> 16);
      }
    }
  }
  float inv = 1.f / den;
  u32_t w[8];
#pragma unroll
  for (int kk = 0; kk < 8; kk++) {
    float o0 = fmaxf(acc[2 * kk] * inv + bias[lane * 16 + 2 * kk], 0.f);
    float o1 = fmaxf(acc[2 * kk + 1] * inv + bias[lane * 16 + 2 * kk + 1], 0.f);
    w[kk] = (u32_t)f2bf(o0) | ((u32_t)f2bf(o1) << 16);
  }
  uint4* op = (uint4*)&h1[(size_t)n * 1024 + lane * 16];
  op[0] = make_uint4(w[0], w[1], w[2], w[3]);
  op[1] = make_uint4(w[4], w[5], w[6], w[7]);
}

// ---------------- GAT2 linear MFMA + att dots ----------------
__global__ __launch_bounds__(256) void k_gat2_lin_mfma(
    const us_t* __restrict__ h1, const us_t* __restrict__ Wt,
    const float* __restrict__ a_s, const float* __restrict__ a_d,
    float* __restrict__ h2pre, float* __restrict__ a2s, float* __restrict__ a2d) {
  __shared__ uint4 AsU[1024];
  __shared__ uint4 BsU[1024];
  char* As = (char*)AsU;
  char* Bs = (char*)BsU;
  int t = threadIdx.x;
  int row0 = blockIdx.x * 64;
  int wv = t >> 6, lane = t & 63, li = lane & 15, lq = lane >> 4;
  f32x4 acc[4];
#pragma unroll
  for (int sub = 0; sub < 4; sub++) acc[sub] = 0;
  for (int kb = 0; kb < 8; kb++) {
    __syncthreads();
    for (int id = t; id < 1024; id += 256) {
      int r = id >> 4, c = id & 15;
      uint4 v = *(const uint4*)&h1[(size_t)(row0 + r) * 1024 + kb * 128 + c * 8];
      *(uint4*)(As + r * 256 + ((c ^ (r & 15)) << 4)) = v;
      uint4 w = *(const uint4*)&Wt[(size_t)r * 1024 + kb * 128 + c * 8];
      *(uint4*)(Bs + r * 256 + ((c ^ (r & 15)) << 4)) = w;
    }
    __syncthreads();
#pragma unroll
    for (int ks = 0; ks < 4; ks++) {
      int r = wv * 16 + li;
      bf16x8 af = *(const bf16x8*)(As + r * 256 + ((((ks << 2) | lq) ^ (r & 15)) << 4));
#pragma unroll
      for (int sub = 0; sub < 4; sub++) {
        int vr = sub * 16 + li;
        bf16x8 bf_ = *(const bf16x8*)(Bs + vr * 256 + ((((ks << 2) | lq) ^ (vr & 15)) << 4));
        acc[sub] = __builtin_amdgcn_mfma_f32_16x16x32_bf16(af, bf_, acc[sub], 0, 0, 0);
      }
    }
  }
  float asv[4], adv[4];
#pragma unroll
  for (int sub = 0; sub < 4; sub++) {
    asv[sub] = a_s[sub * 16 + li];
    adv[sub] = a_d[sub * 16 + li];
  }
#pragma unroll
  for (int rr = 0; rr < 4; rr++) {
    int n = row0 + wv * 16 + lq * 4 + rr;
    float s = 0.f, d = 0.f;
#pragma unroll
    for (int sub = 0; sub < 4; sub++) {
      float hv = acc[sub][rr];
      h2pre[(size_t)n * 64 + sub * 16 + li] = hv;
      s += hv * asv[sub];
      d += hv * adv[sub];
    }
    s = redu16(s); d = redu16(d);
    if (li == 0) { a2s[n] = s; a2d[n] = d; }
  }
}

// ---------------- GAT2 aggregation -> sess ----------------
__global__ void k_gat2_agg(const float* __restrict__ h2pre,
                           const float* __restrict__ a2s, const float* __restrict__ a2d,
                           const float* __restrict__ g, const float* __restrict__ b2,
                           int intr, const int* __restrict__ offsets,
                           const int* __restrict__ adj, float* __restrict__ sess) {
  int gid = blockIdx.x * blockDim.x + threadIdx.x;
  int n = gid >> 6, lane = gid & 63;
  if (n >= NN) return;
  bool nvalid = g[n * 4 + intr] > (1.0f / 3.0f);
  float ad = a2d[n];
  float ls = lrelu(a2s[n] + ad);
  float m = ls;
  int beg = offsets[n], end = offsets[n + 1];
  if (nvalid) {
    for (int j = beg; j < end; j++) {
      int s = adj[j];
      if (g[s * 4 + intr] > (1.0f / 3.0f)) m = fmaxf(m, lrelu(a2s[s] + ad));
    }
  }
  float p = __expf(ls - m);
  float den = p;
  float acc = p * h2pre[(size_t)n * 64 + lane];
  if (nvalid) {
    for (int j = beg; j < end; j++) {
      int s = adj[j];
      if (g[s * 4 + intr] > (1.0f / 3.0f)) {
        float w2 = __expf(lrelu(a2s[s] + ad) - m);
        den += w2;
        acc += w2 * h2pre[(size_t)s * 64 + lane];
      }
    }
  }
  sess[(size_t)n * 192 + intr * 64 + lane] = acc / den + b2[lane];
}

// ---------------- scoring ----------------
__global__ __launch_bounds__(192) void k_vq1(
    const float* __restrict__ sess,
    const float* __restrict__ W1w, const float* __restrict__ W1b,
    float* __restrict__ vn, float* __restrict__ vq1) {
  __shared__ float row[192];
  int b = blockIdx.x, j = threadIdx.x;
  int li = b * 32 + 31;  // batch = repeat(arange(B),32): last node of session b
  float v = sess[(size_t)li * 192 + j];
  row[j] = v;
  vn[b * 192 + j] = v;
  __syncthreads();
  float acc = W1b[j];
  for (int k = 0; k < 192; k++) acc += row[k] * W1w[k * 192 + j];
  vq1[b * 192 + j] = acc;
}

// ---------------- alpha + s_g: MFMA q2, in-block session reduce, no atomics ----------------
__global__ __launch_bounds__(256) void k_alpha_sg_mfma(
    const float* __restrict__ sess, const float* __restrict__ vq1,
    const us_t* __restrict__ W2T, const float* __restrict__ W2b,
    const float* __restrict__ qw, const float* __restrict__ qb,
    float* __restrict__ sg) {
  __shared__ char As[64 * 512];   // 64 rows x 24 (pad 32) 16B-chunks, swizzled
  __shared__ float vq_l[2 * 192];
  __shared__ float w2b_l[192], qw_l[192];
  __shared__ float sg_l[2 * 192];
  int t = threadIdx.x;
  int n0 = blockIdx.x * 64;
  if (t < 192) { w2b_l[t] = W2b[t]; qw_l[t] = qw[t]; }
  for (int id = t; id < 384; id += 256) {
    sg_l[id] = 0.f;
    vq_l[id] = vq1[(size_t)(blockIdx.x * 2) * 192 + id];
  }
  for (int id = t; id < 1536; id += 256) {
    int r = id / 24, c = id % 24;
    const float* p = &sess[(size_t)(n0 + r) * 192 + c * 8];
    float4 f0 = *(const float4*)p;
    float4 f1 = *(const float4*)(p + 4);
    u32_t w0 = (u32_t)f2bf(f0.x) | ((u32_t)f2bf(f0.y) << 16);
    u32_t w1 = (u32_t)f2bf(f0.z) | ((u32_t)f2bf(f0.w) << 16);
    u32_t w2 = (u32_t)f2bf(f1.x) | ((u32_t)f2bf(f1.y) << 16);
    u32_t w3 = (u32_t)f2bf(f1.z) | ((u32_t)f2bf(f1.w) << 16);
    *(uint4*)(As + r * 512 + ((c ^ (r & 7)) << 4)) = make_uint4(w0, w1, w2, w3);
  }
  __syncthreads();
  int wv = t >> 6, lane = t & 63, li = lane & 15, lq = lane >> 4;
  int sl = wv >> 1;
  f32x4 acc[12];
#pragma unroll
  for (int sub = 0; sub < 12; sub++) acc[sub] = 0;
#pragma unroll
  for (int ks = 0; ks < 6; ks++) {
    int r = wv * 16 + li;
    bf16x8 af = *(const bf16x8*)(As + r * 512 + (((ks * 4 + lq) ^ (r & 7)) << 4));
#pragma unroll
    for (int sub = 0; sub < 12; sub++) {
      bf16x8 bfr = *(const bf16x8*)&W2T[(size_t)(sub * 16 + li) * 192 + ks * 32 + lq * 8];
      acc[sub] = __builtin_amdgcn_mfma_f32_16x16x32_bf16(af, bfr, acc[sub], 0, 0, 0);
    }
  }
  float qbv = qb[0];
  float s_part[12];
#pragma unroll
  for (int sub = 0; sub < 12; sub++) s_part[sub] = 0.f;
#pragma unroll
  for (int rr = 0; rr < 4; rr++) {
    int n = n0 + wv * 16 + lq * 4 + rr;
    float ap = 0.f;
    float sv[12];
#pragma unroll
    for (int sub = 0; sub < 12; sub++) {
      int col = sub * 16 + li;
      float q = vq_l[sl * 192 + col] + acc[sub][rr] + w2b_l[col];
      float sgm = 1.f / (1.f + __expf(-q));
      ap += sgm * qw_l[col];
      sv[sub] = sess[(size_t)n * 192 + col];
    }
    ap = redu16(ap);
    float alpha = ap + qbv;
#pragma unroll
    for (int sub = 0; sub < 12; sub++) s_part[sub] += alpha * sv[sub];
  }
#pragma unroll
  for (int sub = 0; sub < 12; sub++) {
    float v = s_part[sub];
    v += __shfl_xor(v, 16, 64);
    v += __shfl_xor(v, 32, 64);
    if (lq == 0) atomicAdd(&sg_l[sl * 192 + sub * 16 + li], v);
  }
  __syncthreads();
  for (int id = t; id < 384; id += 256)
    sg[(size_t)(blockIdx.x * 2) * 192 + id] = sg_l[id];
}

__global__ __launch_bounds__(192) void k_sh(
    const float* __restrict__ vn, const float* __restrict__ sg,
    const float* __restrict__ W3w, const float* __restrict__ W3b,
    float* __restrict__ sh) {
  __shared__ float row[384];
  int b = blockIdx.x, j = threadIdx.x;
  row[j] = vn[b * 192 + j];
  row[192 + j] = sg[b * 192 + j];
  __syncthreads();
  float acc = W3b[j];
  for (int k = 0; k < 384; k++) acc += row[k] * W3w[k * 192 + j];
  sh[b * 192 + j] = acc;
}

// ---------------- final MFMA ----------------
__global__ __launch_bounds__(256) void k_final_mfma(
    const float* __restrict__ sh, const us_t* __restrict__ emb_bf,
    void* __restrict__ out, const int* __restrict__ flag) {
  __shared__ uint4 AsU[384];
  __shared__ uint4 BsU[2048];
  char* As = (char*)AsU;
  char* Bs = (char*)BsU;
  int t = threadIdx.x;
  int v0 = blockIdx.x * 256, b0 = blockIdx.y * 16;
  for (int id = t; id < 384; id += 256) {
    int i2 = id >> 7, rem = id & 127, r = rem >> 3, c = rem & 7;
    const float* p = &sh[(size_t)(b0 + r) * 192 + i2 * 64 + c * 8];
    float4 f0 = *(const float4*)p;
    float4 f1 = *(const float4*)(p + 4);
    u32_t w0 = (u32_t)f2bf(f0.x) | ((u32_t)f2bf(f0.y) << 16);
    u32_t w1 = (u32_t)f2bf(f0.z) | ((u32_t)f2bf(f0.w) << 16);
    u32_t w2 = (u32_t)f2bf(f1.x) | ((u32_t)f2bf(f1.y) << 16);
    u32_t w3 = (u32_t)f2bf(f1.z) | ((u32_t)f2bf(f1.w) << 16);
    *(uint4*)(As + i2 * 2048 + r * 128 + ((c ^ (r & 7)) << 4)) = make_uint4(w0, w1, w2, w3);
  }
  for (int id = t; id < 2048; id += 256) {
    int vr = id >> 3, c = id & 7;
    uint4 v = *(const uint4*)&emb_bf[(size_t)(v0 + vr) * 64 + c * 8];
    *(uint4*)(Bs + vr * 128 + ((c ^ (vr & 7)) << 4)) = v;
  }
  __syncthreads();
  int wv = t >> 6, lane = t & 63, li = lane & 15, lq = lane >> 4;
  int cb = wv * 64;
  int isbf = *flag;
  f32x4 acc[3][4];
#pragma unroll
  for (int i = 0; i < 3; i++)
#pragma unroll
    for (int sub = 0; sub < 4; sub++) acc[i][sub] = 0;
#pragma unroll
  for (int ks = 0; ks < 2; ks++) {
    bf16x8 bfr[4];
#pragma unroll
    for (int sub = 0; sub < 4; sub++) {
      int vr = cb + sub * 16 + li;
      bfr[sub] = *(const bf16x8*)(Bs + vr * 128 + ((((ks << 2) | lq) ^ (vr & 7)) << 4));
    }
#pragma unroll
    for (int i = 0; i < 3; i++) {
      bf16x8 af = *(const bf16x8*)(As + i * 2048 + li * 128 + ((((ks << 2) | lq) ^ (li & 7)) << 4));
#pragma unroll
      for (int sub = 0; sub < 4; sub++)
        acc[i][sub] = __builtin_amdgcn_mfma_f32_16x16x32_bf16(af, bfr[sub], acc[i][sub], 0, 0, 0);
    }
  }
#pragma unroll
  for (int sub = 0; sub < 4; sub++) {
    int col = v0 + cb + sub * 16 + li;
#pragma unroll
    for (int rr = 0; rr < 4; rr++) {
      float o = fmaxf(fmaxf(acc[0][sub][rr], acc[1][sub][rr]), acc[2][sub][rr]);
      int b = b0 + lq * 4 + rr;
      if (isbf) ((us_t*)out)[(size_t)b * VV + col] = f2bf(o);
      else ((float*)out)[(size_t)b * VV + col] = o;
    }
  }
}

// ---------------- launcher ----------------
extern "C" void kernel_launch(void* const* d_in, const int* in_sizes, int n_in,
                              void* d_out, int out_size, void* d_ws, size_t ws_size,
                              hipStream_t stream) {
  if (n_in < 21) return;
  const int* x = (const int*)d_in[0];
  const int* ei = (const int*)d_in[1];

  char* ws = (char*)d_ws;
  size_t off = 0;
  auto A = [&](size_t bytes) -> char* {
    char* p = ws + off;
    off += (bytes + 255) & ~(size_t)255;
    return p;
  };
  int* flag = (int*)A(4);
  us_t* emb_bf = (us_t*)A((size_t)VV * 64 * 2);
  us_t* e_bf = (us_t*)A((size_t)NN * 64 * 2);
  us_t* g1Wt = (us_t*)A((size_t)3 * 65536 * 2);
  us_t* g2Wt = (us_t*)A((size_t)3 * 65536 * 2);
  us_t* W2T = (us_t*)A((size_t)36864 * 2);
  float* c_g1as = (float*)A(3072 * 4);
  float* c_g1ad = (float*)A(3072 * 4);
  float* c_g1b = (float*)A(3072 * 4);
  float* c_g2as = (float*)A(192 * 4);
  float* c_g2ad = (float*)A(192 * 4);
  float* c_g2b = (float*)A(192 * 4);
  float* c_W1w = (float*)A(36864 * 4);
  float* c_W1b = (float*)A(192 * 4);
  float* c_W2b = (float*)A(192 * 4);
  float* c_qw = (float*)A(192 * 4);
  float* c_qb = (float*)A(4);
  float* c_W3w = (float*)A(73728 * 4);
  float* c_W3b = (float*)A(192 * 4);
  float* g_buf = (float*)A((size_t)NN * 4 * 4);
  float* asrc = (float*)A((size_t)NN * 16 * 4);
  float* adst = (float*)A((size_t)NN * 16 * 4);
  us_t* h_pre = (us_t*)A((size_t)NN * 1024 * 2);
  us_t* h1 = (us_t*)A((size_t)NN * 1024 * 2);
  float* h2pre = (float*)A((size_t)NN * 64 * 4);
  float* a2s = (float*)A((size_t)NN * 4);
  float* a2d = (float*)A((size_t)NN * 4);
  float* sess = (float*)A((size_t)NN * 192 * 4);
  float* vq1 = (float*)A((size_t)BB * 192 * 4);
  float* sg = (float*)A((size_t)BB * 192 * 4);
  float* vn = (float*)A((size_t)BB * 192 * 4);
  float* shb = (float*)A((size_t)BB * 192 * 4);
  int* counts = (int*)A((size_t)NN * 4);
  int* offsets = (int*)A((size_t)(NN + 1) * 4);
  int* fillpos = (int*)A((size_t)NN * 4);
  int* adj = (int*)A((size_t)EE * 4);
  if (off > ws_size) return;

  hipMemsetAsync(counts, 0, NN * 4, stream);
  hipMemsetAsync(fillpos, 0, NN * 4, stream);

  k_detect<<<1, 64, 0, stream>>>(d_in[3], flag);

  PrepArgs pa;
  int nb = 0, idx = 0;
  auto SEC = [&](const void* s, void* d, int n, int kind) {
    pa.src[idx] = s; pa.dst[idx] = d; pa.n[idx] = n; pa.kind[idx] = kind;
    pa.start[idx] = nb; nb += (n + 255) / 256; idx++;
  };
  SEC(d_in[3], emb_bf, VV * 64, 1);
  SEC(d_in[5], g1Wt, 196608, 2);
  SEC(d_in[9], g2Wt, 196608, 3);
  SEC(d_in[15], W2T, 36864, 4);
  SEC(d_in[6], c_g1as, 3072, 0);
  SEC(d_in[7], c_g1ad, 3072, 0);
  SEC(d_in[8], c_g1b, 3072, 0);
  SEC(d_in[10], c_g2as, 192, 0);
  SEC(d_in[11], c_g2ad, 192, 0);
  SEC(d_in[12], c_g2b, 192, 0);
  SEC(d_in[13], c_W1w, 36864, 0);
  SEC(d_in[14], c_W1b, 192, 0);
  SEC(d_in[16], c_W2b, 192, 0);
  SEC(d_in[17], c_qw, 192, 0);
  SEC(d_in[18], c_qb, 1, 0);
  SEC(d_in[19], c_W3w, 73728, 0);
  SEC(d_in[20], c_W3b, 192, 0);
  pa.start[17] = nb;
  k_prep<<<nb, 256, 0, stream>>>(pa, flag);

  k_embed<<<NN * 64 / 256, 256, 0, stream>>>(x, d_in[3], d_in[4], flag, e_bf, g_buf);
  k_count<<<EE / 256, 256, 0, stream>>>(ei + EE, counts);
  k_scan<<<1, 256, 0, stream>>>(counts, offsets);
  k_fill<<<EE / 256, 256, 0, stream>>>(ei, ei + EE, offsets, fillpos, adj);

  for (int i = 0; i < 3; i++) {
    k_gat1_lin_mfma<<<dim3(4, NN / 64), 256, 0, stream>>>(
        e_bf, g_buf, g1Wt + (size_t)i * 65536, c_g1as + i * 1024, c_g1ad + i * 1024,
        i, h_pre, asrc, adst);
    k_gat1_agg2<<<NN / 4, 256, 0, stream>>>(
        h_pre, asrc, adst, g_buf, c_g1b + i * 1024, i, offsets, adj, h1);
    k_gat2_lin_mfma<<<NN / 64, 256, 0, stream>>>(
        h1, g2Wt + (size_t)i * 65536, c_g2as + i * 64, c_g2ad + i * 64,
        h2pre, a2s, a2d);
    k_gat2_agg<<<NN * 64 / 256, 256, 0, stream>>>(
        h2pre, a2s, a2d, g_buf, c_g2b + i * 64, i, offsets, adj, sess);
  }

  k_vq1<<<BB, 192, 0, stream>>>(sess, c_W1w, c_W1b, vn, vq1);
  k_alpha_sg_mfma<<<NN / 64, 256, 0, stream>>>(sess, vq1, W2T, c_W2b, c_qw, c_qb, sg);
  k_sh<<<BB, 192, 0, stream>>>(vn, sg, c_W3w, c_W3b, shb);
  k_final_mfma<<<dim3(VV / 256, BB / 16), 256, 0, stream>>>(shb, emb_bf, d_out, flag);
}

// Round 4
// 340.235 us; speedup vs baseline: 2.5899x; 1.0582x over previous
//
#include <hip/hip_runtime.h>
#include <math.h>

#define NN 16384
#define EE 65536
#define BB 512
#define VV 32000

typedef unsigned short us_t;
typedef unsigned int u32_t;
typedef __attribute__((ext_vector_type(4))) float f32x4;
typedef __attribute__((ext_vector_type(8))) short bf16x8;

__device__ __forceinline__ float bf2f(unsigned int u) {
  return __uint_as_float((u & 0xffffu) << 16);
}
__device__ __forceinline__ unsigned short f2bf(float f) {
  unsigned int x = __float_as_uint(f);
  unsigned int r = (x + 0x7fffu + ((x >> 16) & 1u)) >> 16;
  return (unsigned short)r;
}
__device__ __forceinline__ float wsum(float v) {
#pragma unroll
  for (int o = 32; o; o >>= 1) v += __shfl_xor(v, o, 64);
  return v;
}
__device__ __forceinline__ float redu16(float v) {
  v += __shfl_xor(v, 1, 64);
  v += __shfl_xor(v, 2, 64);
  v += __shfl_xor(v, 4, 64);
  v += __shfl_xor(v, 8, 64);
  return v;
}
__device__ __forceinline__ float lrelu(float x) { return x > 0.f ? x : 0.2f * x; }

// ---------------- dtype probe ----------------
__global__ void k_detect(const void* emb, int* flag) {
  if (threadIdx.x == 0 && blockIdx.x == 0) {
    const us_t* u = (const us_t*)emb;
    int ok = 1;
    for (int i = 0; i < 128; i++) {
      float v = bf2f((unsigned int)u[i]);
      if (!(fabsf(v) <= 0.13f)) { ok = 0; break; }
    }
    *flag = ok;  // 1 => inputs bf16, 0 => f32
  }
}

// ---------------- fused prep: convert + transpose weights ----------------
struct PrepArgs {
  const void* src[17];
  void* dst[17];
  int n[17];
  int kind[17];   // 0 cvt f32, 1 cvt bf16, 2 g1W T, 3 g2W T, 4 W2 T (192x192)
  int start[18];
};

__global__ void k_prep(PrepArgs pa, const int* __restrict__ flag) {
  int blk = blockIdx.x;
  int s = 0;
  while (s < 16 && blk >= pa.start[s + 1]) s++;
  int i = (blk - pa.start[s]) * 256 + threadIdx.x;
  if (i >= pa.n[s]) return;
  float v = (*flag) ? bf2f((unsigned int)((const us_t*)pa.src[s])[i])
                    : ((const float*)pa.src[s])[i];
  int kind = pa.kind[s];
  if (kind == 0) {
    ((float*)pa.dst[s])[i] = v;
  } else if (kind == 1) {
    ((us_t*)pa.dst[s])[i] = f2bf(v);
  } else if (kind == 2) {  // [3][64][1024] -> [3][1024][64]
    int ii = i >> 16, r = i & 65535, k = r >> 10, col = r & 1023;
    ((us_t*)pa.dst[s])[(ii << 16) + col * 64 + k] = f2bf(v);
  } else if (kind == 3) {  // [3][1024][64] -> [3][64][1024]
    int ii = i >> 16, r = i & 65535, k = r >> 6, col = r & 63;
    ((us_t*)pa.dst[s])[(ii << 16) + col * 1024 + k] = f2bf(v);
  } else {  // [192][192] -> [192][192]^T
    int k = i / 192, col = i % 192;
    ((us_t*)pa.dst[s])[col * 192 + k] = f2bf(v);
  }
}

// ---------------- Waspack: [96 cols][64 k] bf16; col = i*32 + sd*16 + h ----------------
__global__ void k_prepWa(const void* __restrict__ g1Wraw,
                         const float* __restrict__ g1as, const float* __restrict__ g1ad,
                         const int* __restrict__ flag, us_t* __restrict__ Waspack) {
  int gid = blockIdx.x * 256 + threadIdx.x;
  if (gid >= 96 * 64) return;
  int c = gid >> 6, k = gid & 63;
  int i = c >> 5, sd = (c >> 4) & 1, h = c & 15;
  const float* av = (sd ? g1ad : g1as) + i * 1024 + h * 64;
  size_t base = (size_t)i * 65536 + (size_t)k * 1024 + h * 64;
  int isbf = *flag;
  float s = 0.f;
  for (int d = 0; d < 64; d++) {
    float wv = isbf ? bf2f((unsigned int)((const us_t*)g1Wraw)[base + d])
                    : ((const float*)g1Wraw)[base + d];
    s += wv * av[d];
  }
  Waspack[c * 64 + k] = f2bf(s);
}

// ---------------- embedding gather + interest softmax ----------------
__global__ void k_embed(const int* __restrict__ x, const void* __restrict__ embr,
                        const void* __restrict__ wintr, const int* __restrict__ flag,
                        us_t* __restrict__ e_bf, float* __restrict__ g) {
  int gid = blockIdx.x * blockDim.x + threadIdx.x;
  int n = gid >> 6, lane = gid & 63;
  if (n >= NN) return;
  int isbf = *flag;
  size_t ei = (size_t)x[n] * 64 + lane;
  float v = isbf ? bf2f((unsigned int)((const us_t*)embr)[ei]) : ((const float*)embr)[ei];
  e_bf[(size_t)n * 64 + lane] = f2bf(v);
  float w0, w1, w2;
  if (isbf) {
    const us_t* w = (const us_t*)wintr;
    w0 = bf2f(w[lane * 3 + 0]); w1 = bf2f(w[lane * 3 + 1]); w2 = bf2f(w[lane * 3 + 2]);
  } else {
    const float* w = (const float*)wintr;
    w0 = w[lane * 3 + 0]; w1 = w[lane * 3 + 1]; w2 = w[lane * 3 + 2];
  }
  float t0 = wsum(v * w0), t1 = wsum(v * w1), t2 = wsum(v * w2);
  if (lane == 0) {
    float l0 = t0 / 0.1f, l1 = t1 / 0.1f, l2 = t2 / 0.1f;
    float m = fmaxf(l0, fmaxf(l1, l2));
    float p0 = __expf(l0 - m), p1 = __expf(l1 - m), p2 = __expf(l2 - m);
    float inv = 1.0f / (p0 + p1 + p2);
    g[n * 4 + 0] = p0 * inv; g[n * 4 + 1] = p1 * inv;
    g[n * 4 + 2] = p2 * inv; g[n * 4 + 3] = 0.f;
  }
}

// ---------------- CSR build ----------------
__global__ void k_count(const int* __restrict__ dst, int* __restrict__ counts) {
  int e = blockIdx.x * blockDim.x + threadIdx.x;
  if (e < EE) atomicAdd(&counts[dst[e]], 1);
}

__global__ void k_scan(const int* __restrict__ counts, int* __restrict__ offsets) {
  __shared__ int part[256];
  __shared__ int excl[257];
  int t = threadIdx.x;
  int base = t * 64;
  int s = 0;
  for (int j = 0; j < 64; j++) s += counts[base + j];
  part[t] = s;
  __syncthreads();
  if (t == 0) {
    int run = 0;
    for (int j = 0; j < 256; j++) { excl[j] = run; run += part[j]; }
    excl[256] = run;
  }
  __syncthreads();
  int run = excl[t];
  for (int j = 0; j < 64; j++) { offsets[base + j] = run; run += counts[base + j]; }
  if (t == 255) offsets[NN] = excl[256];
}

__global__ void k_fill(const int* __restrict__ src, const int* __restrict__ dst,
                       const int* __restrict__ offsets, int* __restrict__ fillpos,
                       int* __restrict__ adj) {
  int e = blockIdx.x * blockDim.x + threadIdx.x;
  if (e < EE) {
    int d = dst[e];
    int pos = offsets[d] + atomicAdd(&fillpos[d], 1);
    adj[pos] = src[e];
  }
}

// ---------------- easrc: e[N,64] @ Waspack^T -> eatt[N][96] f32 ----------------
__global__ __launch_bounds__(256) void k_easrc(
    const us_t* __restrict__ e_bf, const us_t* __restrict__ Waspack,
    float* __restrict__ eatt) {
  __shared__ char As[8192];
  int t = threadIdx.x;
  int row0 = blockIdx.x * 64;
  for (int id = t; id < 512; id += 256) {
    int r = id >> 3, c = id & 7;
    uint4 v = *(const uint4*)&e_bf[(size_t)(row0 + r) * 64 + c * 8];
    *(uint4*)(As + r * 128 + ((c ^ (r & 7)) << 4)) = v;
  }
  __syncthreads();
  int wv = t >> 6, L = t & 63, li = L & 15, lq = L >> 4;
#pragma unroll
  for (int ct = 0; ct < 6; ct++) {
    f32x4 acc = {0.f, 0.f, 0.f, 0.f};
#pragma unroll
    for (int ks = 0; ks < 2; ks++) {
      int row = wv * 16 + li;
      bf16x8 af = *(const bf16x8*)(As + row * 128 + (((ks * 4 + lq) ^ (row & 7)) << 4));
      bf16x8 bfr = *(const bf16x8*)(Waspack + (size_t)(ct * 16 + li) * 64 + ks * 32 + lq * 8);
      acc = __builtin_amdgcn_mfma_f32_16x16x32_bf16(af, bfr, acc, 0, 0, 0);
    }
#pragma unroll
    for (int r = 0; r < 4; r++) {
      int row = row0 + wv * 16 + lq * 4 + r;
      eatt[(size_t)row * 96 + ct * 16 + li] = acc[r];
    }
  }
}

// ---------------- FUSED GAT: x-space aggregation + per-head W1/relu/W2 ----------------
// grid (NN/32, 3). Per block: 32 nodes, one interest. No h_pre/h1 in HBM.
__global__ __launch_bounds__(256) void k_gat_fused(
    const us_t* __restrict__ e_bf, const float* __restrict__ g,
    const float* __restrict__ eatt, const us_t* __restrict__ g1Wt,
    const us_t* __restrict__ g2Wt, const float* __restrict__ b1all,
    const float* __restrict__ g2as, const float* __restrict__ g2ad,
    const int* __restrict__ offsets, const int* __restrict__ adj,
    float* __restrict__ h2pre, float* __restrict__ a2s, float* __restrict__ a2d) {
  __shared__ char xagg[32 * 2048];     // [32 nodes][16 heads*64 xdims] bf16, swizzled
  __shared__ char Tbuf[2][32 * 128];   // h1 tile per head [32][64] bf16, swizzled
  __shared__ float a2sl[32], a2dl[32];
  int t = threadIdx.x;
  int intr = blockIdx.y;
  int n0 = blockIdx.x * 32;
  int wv = t >> 6, L = t & 63, li = L & 15, lq = L >> 4;
  const us_t* Wt1 = g1Wt + (size_t)intr * 65536;
  const us_t* Wt2 = g2Wt + (size_t)intr * 65536;
  const float* b1 = b1all + intr * 1024;
  const float* as2 = g2as + intr * 64;
  const float* ad2 = g2ad + intr * 64;
  if (t < 32) { a2sl[t] = 0.f; a2dl[t] = 0.f; }
  // ---- Phase A: x-space online-softmax aggregation (wave-per-node) ----
  int h = L >> 2;
  int doff = (L & 3) * 16;
  const float thr = 1.0f / 3.0f;
  for (int k = 0; k < 8; k++) {
    int nl = wv * 8 + k;
    int n = n0 + nl;
    float gn = g[n * 4 + intr];
    float ad = gn * eatt[(size_t)n * 96 + intr * 32 + 16 + h];
    float m = lrelu(gn * eatt[(size_t)n * 96 + intr * 32 + h] + ad);
    float den = 1.f;
    float acc[16];
    {
      const uint4* ep = (const uint4*)&e_bf[(size_t)n * 64 + doff];
      uint4 a = ep[0], b = ep[1];
      acc[0] = gn * bf2f(a.x);  acc[1] = gn * bf2f(a.x >> 16);
      acc[2] = gn * bf2f(a.y);  acc[3] = gn * bf2f(a.y >> 16);
      acc[4] = gn * bf2f(a.z);  acc[5] = gn * bf2f(a.z >> 16);
      acc[6] = gn * bf2f(a.w);  acc[7] = gn * bf2f(a.w >> 16);
      acc[8] = gn * bf2f(b.x);  acc[9] = gn * bf2f(b.x >> 16);
      acc[10] = gn * bf2f(b.y); acc[11] = gn * bf2f(b.y >> 16);
      acc[12] = gn * bf2f(b.z); acc[13] = gn * bf2f(b.z >> 16);
      acc[14] = gn * bf2f(b.w); acc[15] = gn * bf2f(b.w >> 16);
    }
    if (gn > thr) {
      int beg = offsets[n], end = offsets[n + 1];
      for (int j = beg; j < end; j++) {
        int s = adj[j];
        float gs = g[s * 4 + intr];
        if (gs > thr) {
          float l = lrelu(gs * eatt[(size_t)s * 96 + intr * 32 + h] + ad);
          if (l > m) {
            float sc = __expf(m - l);
            den *= sc;
#pragma unroll
            for (int q = 0; q < 16; q++) acc[q] *= sc;
            m = l;
          }
          float p = __expf(l - m);
          den += p;
          float pg = p * gs;
          const uint4* ep = (const uint4*)&e_bf[(size_t)s * 64 + doff];
          uint4 a = ep[0], b = ep[1];
          acc[0] += pg * bf2f(a.x);  acc[1] += pg * bf2f(a.x >> 16);
          acc[2] += pg * bf2f(a.y);  acc[3] += pg * bf2f(a.y >> 16);
          acc[4] += pg * bf2f(a.z);  acc[5] += pg * bf2f(a.z >> 16);
          acc[6] += pg * bf2f(a.w);  acc[7] += pg * bf2f(a.w >> 16);
          acc[8] += pg * bf2f(b.x);  acc[9] += pg * bf2f(b.x >> 16);
          acc[10] += pg * bf2f(b.y); acc[11] += pg * bf2f(b.y >> 16);
          acc[12] += pg * bf2f(b.z); acc[13] += pg * bf2f(b.z >> 16);
          acc[14] += pg * bf2f(b.w); acc[15] += pg * bf2f(b.w >> 16);
        }
      }
    }
    float inv = 1.f / den;
    u32_t w[8];
#pragma unroll
    for (int kk = 0; kk < 8; kk++) {
      w[kk] = (u32_t)f2bf(acc[2 * kk] * inv) | ((u32_t)f2bf(acc[2 * kk + 1] * inv) << 16);
    }
    int c0 = h * 8 + (L & 3) * 2;
    *(uint4*)(xagg + nl * 2048 + ((c0 ^ (nl & 7)) << 4)) = make_uint4(w[0], w[1], w[2], w[3]);
    *(uint4*)(xagg + nl * 2048 + (((c0 + 1) ^ (nl & 7)) << 4)) = make_uint4(w[4], w[5], w[6], w[7]);
  }
  __syncthreads();
  // ---- Phase B: per head: T = relu(xagg_h @ W1_h + b1); h2 += T @ W2_h ----
  int rt = wv & 1, ctb = (wv >> 1) * 2;
  f32x4 acc2[2];
  acc2[0] = {0.f, 0.f, 0.f, 0.f};
  acc2[1] = {0.f, 0.f, 0.f, 0.f};
  for (int hh = 0; hh < 16; hh++) {
    f32x4 c1[2];
    c1[0] = {0.f, 0.f, 0.f, 0.f};
    c1[1] = {0.f, 0.f, 0.f, 0.f};
#pragma unroll
    for (int ks = 0; ks < 2; ks++) {
      int row = rt * 16 + li;
      int ca = hh * 8 + ks * 4 + lq;
      bf16x8 af = *(const bf16x8*)(xagg + row * 2048 + ((ca ^ (row & 7)) << 4));
#pragma unroll
      for (int c2 = 0; c2 < 2; c2++) {
        int oc = hh * 64 + (ctb + c2) * 16 + li;
        bf16x8 bfr = *(const bf16x8*)(Wt1 + (size_t)oc * 64 + ks * 32 + lq * 8);
        c1[c2] = __builtin_amdgcn_mfma_f32_16x16x32_bf16(af, bfr, c1[c2], 0, 0, 0);
      }
    }
    char* Tb = Tbuf[hh & 1];
#pragma unroll
    for (int c2 = 0; c2 < 2; c2++) {
      int col = (ctb + c2) * 16 + li;
      float bv = b1[hh * 64 + col];
#pragma unroll
      for (int r = 0; r < 4; r++) {
        int row = rt * 16 + lq * 4 + r;
        float tv = fmaxf(c1[c2][r] + bv, 0.f);
        int cc = (col * 2) >> 4;
        *(us_t*)(Tb + row * 128 + ((cc ^ (row & 7)) << 4) + ((col * 2) & 15)) = f2bf(tv);
      }
    }
    __syncthreads();
#pragma unroll
    for (int ks = 0; ks < 2; ks++) {
      int row = rt * 16 + li;
      int cc = ks * 4 + lq;
      bf16x8 af2 = *(const bf16x8*)(Tb + row * 128 + ((cc ^ (row & 7)) << 4));
#pragma unroll
      for (int c2 = 0; c2 < 2; c2++) {
        int oc = (ctb + c2) * 16 + li;
        bf16x8 bfr = *(const bf16x8*)(Wt2 + (size_t)oc * 1024 + hh * 64 + ks * 32 + lq * 8);
        acc2[c2] = __builtin_amdgcn_mfma_f32_16x16x32_bf16(af2, bfr, acc2[c2], 0, 0, 0);
      }
    }
  }
  // ---- epilogue: write h2pre, accumulate a2s/a2d ----
  float ps[4] = {0.f, 0.f, 0.f, 0.f}, pd[4] = {0.f, 0.f, 0.f, 0.f};
#pragma unroll
  for (int c2 = 0; c2 < 2; c2++) {
    int col = (ctb + c2) * 16 + li;
    float asv = as2[col], adv = ad2[col];
#pragma unroll
    for (int r = 0; r < 4; r++) {
      int row = rt * 16 + lq * 4 + r;
      float v = acc2[c2][r];
      h2pre[((size_t)intr * NN + n0 + row) * 64 + col] = v;
      ps[r] += v * asv;
      pd[r] += v * adv;
    }
  }
#pragma unroll
  for (int r = 0; r < 4; r++) { ps[r] = redu16(ps[r]); pd[r] = redu16(pd[r]); }
  if (li == 0) {
#pragma unroll
    for (int r = 0; r < 4; r++) {
      atomicAdd(&a2sl[rt * 16 + lq * 4 + r], ps[r]);
      atomicAdd(&a2dl[rt * 16 + lq * 4 + r], pd[r]);
    }
  }
  __syncthreads();
  if (t < 32) {
    a2s[(size_t)intr * NN + n0 + t] = a2sl[t];
    a2d[(size_t)intr * NN + n0 + t] = a2dl[t];
  }
}

// ---------------- GAT2 aggregation -> sess (grid.y = interest) ----------------
__global__ void k_gat2_agg(const float* __restrict__ h2pre_a,
                           const float* __restrict__ a2s_a, const float* __restrict__ a2d_a,
                           const float* __restrict__ g, const float* __restrict__ b2all,
                           const int* __restrict__ offsets,
                           const int* __restrict__ adj, float* __restrict__ sess) {
  int intr = blockIdx.y;
  int gid = blockIdx.x * blockDim.x + threadIdx.x;
  int n = gid >> 6, lane = gid & 63;
  if (n >= NN) return;
  const float* h2pre = h2pre_a + (size_t)intr * NN * 64;
  const float* a2s = a2s_a + (size_t)intr * NN;
  const float* a2d = a2d_a + (size_t)intr * NN;
  const float* b2 = b2all + intr * 64;
  bool nvalid = g[n * 4 + intr] > (1.0f / 3.0f);
  float ad = a2d[n];
  float ls = lrelu(a2s[n] + ad);
  float m = ls;
  int beg = offsets[n], end = offsets[n + 1];
  if (nvalid) {
    for (int j = beg; j < end; j++) {
      int s = adj[j];
      if (g[s * 4 + intr] > (1.0f / 3.0f)) m = fmaxf(m, lrelu(a2s[s] + ad));
    }
  }
  float p = __expf(ls - m);
  float den = p;
  float acc = p * h2pre[(size_t)n * 64 + lane];
  if (nvalid) {
    for (int j = beg; j < end; j++) {
      int s = adj[j];
      if (g[s * 4 + intr] > (1.0f / 3.0f)) {
        float w2 = __expf(lrelu(a2s[s] + ad) - m);
        den += w2;
        acc += w2 * h2pre[(size_t)s * 64 + lane];
      }
    }
  }
  sess[(size_t)n * 192 + intr * 64 + lane] = acc / den + b2[lane];
}

// ---------------- scoring ----------------
__global__ __launch_bounds__(192) void k_vq1(
    const float* __restrict__ sess,
    const float* __restrict__ W1w, const float* __restrict__ W1b,
    float* __restrict__ vn, float* __restrict__ vq1) {
  __shared__ float row[192];
  int b = blockIdx.x, j = threadIdx.x;
  int li = b * 32 + 31;  // batch = repeat(arange(B),32)
  float v = sess[(size_t)li * 192 + j];
  row[j] = v;
  vn[b * 192 + j] = v;
  __syncthreads();
  float acc = W1b[j];
  for (int k = 0; k < 192; k++) acc += row[k] * W1w[k * 192 + j];
  vq1[b * 192 + j] = acc;
}

__global__ __launch_bounds__(256) void k_alpha_sg_mfma(
    const float* __restrict__ sess, const float* __restrict__ vq1,
    const us_t* __restrict__ W2T, const float* __restrict__ W2b,
    const float* __restrict__ qw, const float* __restrict__ qb,
    float* __restrict__ sg) {
  __shared__ char As[64 * 512];
  __shared__ float vq_l[2 * 192];
  __shared__ float w2b_l[192], qw_l[192];
  __shared__ float sg_l[2 * 192];
  int t = threadIdx.x;
  int n0 = blockIdx.x * 64;
  if (t < 192) { w2b_l[t] = W2b[t]; qw_l[t] = qw[t]; }
  for (int id = t; id < 384; id += 256) {
    sg_l[id] = 0.f;
    vq_l[id] = vq1[(size_t)(blockIdx.x * 2) * 192 + id];
  }
  for (int id = t; id < 1536; id += 256) {
    int r = id / 24, c = id % 24;
    const float* p = &sess[(size_t)(n0 + r) * 192 + c * 8];
    float4 f0 = *(const float4*)p;
    float4 f1 = *(const float4*)(p + 4);
    u32_t w0 = (u32_t)f2bf(f0.x) | ((u32_t)f2bf(f0.y) << 16);
    u32_t w1 = (u32_t)f2bf(f0.z) | ((u32_t)f2bf(f0.w) << 16);
    u32_t w2 = (u32_t)f2bf(f1.x) | ((u32_t)f2bf(f1.y) << 16);
    u32_t w3 = (u32_t)f2bf(f1.z) | ((u32_t)f2bf(f1.w) << 16);
    *(uint4*)(As + r * 512 + ((c ^ (r & 7)) << 4)) = make_uint4(w0, w1, w2, w3);
  }
  __syncthreads();
  int wv = t >> 6, lane = t & 63, li = lane & 15, lq = lane >> 4;
  int sl = wv >> 1;
  f32x4 acc[12];
#pragma unroll
  for (int sub = 0; sub < 12; sub++) acc[sub] = {0.f, 0.f, 0.f, 0.f};
#pragma unroll
  for (int ks = 0; ks < 6; ks++) {
    int r = wv * 16 + li;
    bf16x8 af = *(const bf16x8*)(As + r * 512 + (((ks * 4 + lq) ^ (r & 7)) << 4));
#pragma unroll
    for (int sub = 0; sub < 12; sub++) {
      bf16x8 bfr = *(const bf16x8*)&W2T[(size_t)(sub * 16 + li) * 192 + ks * 32 + lq * 8];
      acc[sub] = __builtin_amdgcn_mfma_f32_16x16x32_bf16(af, bfr, acc[sub], 0, 0, 0);
    }
  }
  float qbv = qb[0];
  float s_part[12];
#pragma unroll
  for (int sub = 0; sub < 12; sub++) s_part[sub] = 0.f;
#pragma unroll
  for (int rr = 0; rr < 4; rr++) {
    int n = n0 + wv * 16 + lq * 4 + rr;
    float ap = 0.f;
    float sv[12];
#pragma unroll
    for (int sub = 0; sub < 12; sub++) {
      int col = sub * 16 + li;
      float q = vq_l[sl * 192 + col] + acc[sub][rr] + w2b_l[col];
      float sgm = 1.f / (1.f + __expf(-q));
      ap += sgm * qw_l[col];
      sv[sub] = sess[(size_t)n * 192 + col];
    }
    ap = redu16(ap);
    float alpha = ap + qbv;
#pragma unroll
    for (int sub = 0; sub < 12; sub++) s_part[sub] += alpha * sv[sub];
  }
#pragma unroll
  for (int sub = 0; sub < 12; sub++) {
    float v = s_part[sub];
    v += __shfl_xor(v, 16, 64);
    v += __shfl_xor(v, 32, 64);
    if (lq == 0) atomicAdd(&sg_l[sl * 192 + sub * 16 + li], v);
  }
  __syncthreads();
  for (int id = t; id < 384; id += 256)
    sg[(size_t)(blockIdx.x * 2) * 192 + id] = sg_l[id];
}

__global__ __launch_bounds__(192) void k_sh(
    const float* __restrict__ vn, const float* __restrict__ sg,
    const float* __restrict__ W3w, const float* __restrict__ W3b,
    float* __restrict__ sh) {
  __shared__ float row[384];
  int b = blockIdx.x, j = threadIdx.x;
  row[j] = vn[b * 192 + j];
  row[192 + j] = sg[b * 192 + j];
  __syncthreads();
  float acc = W3b[j];
  for (int k = 0; k < 384; k++) acc += row[k] * W3w[k * 192 + j];
  sh[b * 192 + j] = acc;
}

// ---------------- final MFMA ----------------
__global__ __launch_bounds__(256) void k_final_mfma(
    const float* __restrict__ sh, const us_t* __restrict__ emb_bf,
    void* __restrict__ out, const int* __restrict__ flag) {
  __shared__ uint4 AsU[384];
  __shared__ uint4 BsU[2048];
  char* As = (char*)AsU;
  char* Bs = (char*)BsU;
  int t = threadIdx.x;
  int v0 = blockIdx.x * 256, b0 = blockIdx.y * 16;
  for (int id = t; id < 384; id += 256) {
    int i2 = id >> 7, rem = id & 127, r = rem >> 3, c = rem & 7;
    const float* p = &sh[(size_t)(b0 + r) * 192 + i2 * 64 + c * 8];
    float4 f0 = *(const float4*)p;
    float4 f1 = *(const float4*)(p + 4);
    u32_t w0 = (u32_t)f2bf(f0.x) | ((u32_t)f2bf(f0.y) << 16);
    u32_t w1 = (u32_t)f2bf(f0.z) | ((u32_t)f2bf(f0.w) << 16);
    u32_t w2 = (u32_t)f2bf(f1.x) | ((u32_t)f2bf(f1.y) << 16);
    u32_t w3 = (u32_t)f2bf(f1.z) | ((u32_t)f2bf(f1.w) << 16);
    *(uint4*)(As + i2 * 2048 + r * 128 + ((c ^ (r & 7)) << 4)) = make_uint4(w0, w1, w2, w3);
  }
  for (int id = t; id < 2048; id += 256) {
    int vr = id >> 3, c = id & 7;
    uint4 v = *(const uint4*)&emb_bf[(size_t)(v0 + vr) * 64 + c * 8];
    *(uint4*)(Bs + vr * 128 + ((c ^ (vr & 7)) << 4)) = v;
  }
  __syncthreads();
  int wv = t >> 6, lane = t & 63, li = lane & 15, lq = lane >> 4;
  int cb = wv * 64;
  int isbf = *flag;
  f32x4 acc[3][4];
#pragma unroll
  for (int i = 0; i < 3; i++)
#pragma unroll
    for (int sub = 0; sub < 4; sub++) acc[i][sub] = {0.f, 0.f, 0.f, 0.f};
#pragma unroll
  for (int ks = 0; ks < 2; ks++) {
    bf16x8 bfr[4];
#pragma unroll
    for (int sub = 0; sub < 4; sub++) {
      int vr = cb + sub * 16 + li;
      bfr[sub] = *(const bf16x8*)(Bs + vr * 128 + ((((ks << 2) | lq) ^ (vr & 7)) << 4));
    }
#pragma unroll
    for (int i = 0; i < 3; i++) {
      bf16x8 af = *(const bf16x8*)(As + i * 2048 + li * 128 + ((((ks << 2) | lq) ^ (li & 7)) << 4));
#pragma unroll
      for (int sub = 0; sub < 4; sub++)
        acc[i][sub] = __builtin_amdgcn_mfma_f32_16x16x32_bf16(af, bfr[sub], acc[i][sub], 0, 0, 0);
    }
  }
#pragma unroll
  for (int sub = 0; sub < 4; sub++) {
    int col = v0 + cb + sub * 16 + li;
#pragma unroll
    for (int rr = 0; rr < 4; rr++) {
      float o = fmaxf(fmaxf(acc[0][sub][rr], acc[1][sub][rr]), acc[2][sub][rr]);
      int b = b0 + lq * 4 + rr;
      if (isbf) ((us_t*)out)[(size_t)b * VV + col] = f2bf(o);
      else ((float*)out)[(size_t)b * VV + col] = o;
    }
  }
}

// ---------------- launcher ----------------
extern "C" void kernel_launch(void* const* d_in, const int* in_sizes, int n_in,
                              void* d_out, int out_size, void* d_ws, size_t ws_size,
                              hipStream_t stream) {
  if (n_in < 21) return;
  const int* x = (const int*)d_in[0];
  const int* ei = (const int*)d_in[1];

  char* ws = (char*)d_ws;
  size_t off = 0;
  auto A = [&](size_t bytes) -> char* {
    char* p = ws + off;
    off += (bytes + 255) & ~(size_t)255;
    return p;
  };
  int* flag = (int*)A(4);
  us_t* emb_bf = (us_t*)A((size_t)VV * 64 * 2);
  us_t* e_bf = (us_t*)A((size_t)NN * 64 * 2);
  us_t* g1Wt = (us_t*)A((size_t)3 * 65536 * 2);
  us_t* g2Wt = (us_t*)A((size_t)3 * 65536 * 2);
  us_t* W2T = (us_t*)A((size_t)36864 * 2);
  us_t* Waspack = (us_t*)A((size_t)96 * 64 * 2);
  float* eatt = (float*)A((size_t)NN * 96 * 4);
  float* c_g1as = (float*)A(3072 * 4);
  float* c_g1ad = (float*)A(3072 * 4);
  float* c_g1b = (float*)A(3072 * 4);
  float* c_g2as = (float*)A(192 * 4);
  float* c_g2ad = (float*)A(192 * 4);
  float* c_g2b = (float*)A(192 * 4);
  float* c_W1w = (float*)A(36864 * 4);
  float* c_W1b = (float*)A(192 * 4);
  float* c_W2b = (float*)A(192 * 4);
  float* c_qw = (float*)A(192 * 4);
  float* c_qb = (float*)A(4);
  float* c_W3w = (float*)A(73728 * 4);
  float* c_W3b = (float*)A(192 * 4);
  float* g_buf = (float*)A((size_t)NN * 4 * 4);
  float* h2pre = (float*)A((size_t)3 * NN * 64 * 4);
  float* a2s = (float*)A((size_t)3 * NN * 4);
  float* a2d = (float*)A((size_t)3 * NN * 4);
  float* sess = (float*)A((size_t)NN * 192 * 4);
  float* vq1 = (float*)A((size_t)BB * 192 * 4);
  float* sg = (float*)A((size_t)BB * 192 * 4);
  float* vn = (float*)A((size_t)BB * 192 * 4);
  float* shb = (float*)A((size_t)BB * 192 * 4);
  int* counts = (int*)A((size_t)NN * 4);
  int* offsets = (int*)A((size_t)(NN + 1) * 4);
  int* fillpos = (int*)A((size_t)NN * 4);
  int* adj = (int*)A((size_t)EE * 4);
  if (off > ws_size) return;

  hipMemsetAsync(counts, 0, NN * 4, stream);
  hipMemsetAsync(fillpos, 0, NN * 4, stream);

  k_detect<<<1, 64, 0, stream>>>(d_in[3], flag);

  PrepArgs pa;
  int nb = 0, idx = 0;
  auto SEC = [&](const void* s, void* d, int n, int kind) {
    pa.src[idx] = s; pa.dst[idx] = d; pa.n[idx] = n; pa.kind[idx] = kind;
    pa.start[idx] = nb; nb += (n + 255) / 256; idx++;
  };
  SEC(d_in[3], emb_bf, VV * 64, 1);
  SEC(d_in[5], g1Wt, 196608, 2);
  SEC(d_in[9], g2Wt, 196608, 3);
  SEC(d_in[15], W2T, 36864, 4);
  SEC(d_in[6], c_g1as, 3072, 0);
  SEC(d_in[7], c_g1ad, 3072, 0);
  SEC(d_in[8], c_g1b, 3072, 0);
  SEC(d_in[10], c_g2as, 192, 0);
  SEC(d_in[11], c_g2ad, 192, 0);
  SEC(d_in[12], c_g2b, 192, 0);
  SEC(d_in[13], c_W1w, 36864, 0);
  SEC(d_in[14], c_W1b, 192, 0);
  SEC(d_in[16], c_W2b, 192, 0);
  SEC(d_in[17], c_qw, 192, 0);
  SEC(d_in[18], c_qb, 1, 0);
  SEC(d_in[19], c_W3w, 73728, 0);
  SEC(d_in[20], c_W3b, 192, 0);
  pa.start[17] = nb;
  k_prep<<<nb, 256, 0, stream>>>(pa, flag);
  k_prepWa<<<24, 256, 0, stream>>>(d_in[5], c_g1as, c_g1ad, flag, Waspack);

  k_embed<<<NN * 64 / 256, 256, 0, stream>>>(x, d_in[3], d_in[4], flag, e_bf, g_buf);
  k_count<<<EE / 256, 256, 0, stream>>>(ei + EE, counts);
  k_scan<<<1, 256, 0, stream>>>(counts, offsets);
  k_fill<<<EE / 256, 256, 0, stream>>>(ei, ei + EE, offsets, fillpos, adj);

  k_easrc<<<NN / 64, 256, 0, stream>>>(e_bf, Waspack, eatt);
  k_gat_fused<<<dim3(NN / 32, 3), 256, 0, stream>>>(
      e_bf, g_buf, eatt, g1Wt, g2Wt, c_g1b, c_g2as, c_g2ad,
      offsets, adj, h2pre, a2s, a2d);
  k_gat2_agg<<<dim3(NN * 64 / 256, 3), 256, 0, stream>>>(
      h2pre, a2s, a2d, g_buf, c_g2b, offsets, adj, sess);

  k_vq1<<<BB, 192, 0, stream>>>(sess, c_W1w, c_W1b, vn, vq1);
  k_alpha_sg_mfma<<<NN / 64, 256, 0, stream>>>(sess, vq1, W2T, c_W2b, c_qw, c_qb, sg);
  k_sh<<<BB, 192, 0, stream>>>(vn, sg, c_W3w, c_W3b, shb);
  k_final_mfma<<<dim3(VV / 256, BB / 16), 256, 0, stream>>>(shb, emb_bf, d_out, flag);
}

// Round 5
// 301.862 us; speedup vs baseline: 2.9191x; 1.1271x over previous
//
#include <hip/hip_runtime.h>
#include <math.h>

#define NN 16384
#define EE 65536
#define BB 512
#define VV 32000

typedef unsigned short us_t;
typedef unsigned int u32_t;
typedef __attribute__((ext_vector_type(4))) float f32x4;
typedef __attribute__((ext_vector_type(8))) short bf16x8;

__device__ __forceinline__ float bf2f(unsigned int u) {
  return __uint_as_float((u & 0xffffu) << 16);
}
__device__ __forceinline__ unsigned short f2bf(float f) {
  unsigned int x = __float_as_uint(f);
  unsigned int r = (x + 0x7fffu + ((x >> 16) & 1u)) >> 16;
  return (unsigned short)r;
}
__device__ __forceinline__ float wsum(float v) {
#pragma unroll
  for (int o = 32; o; o >>= 1) v += __shfl_xor(v, o, 64);
  return v;
}
__device__ __forceinline__ float redu16(float v) {
  v += __shfl_xor(v, 1, 64);
  v += __shfl_xor(v, 2, 64);
  v += __shfl_xor(v, 4, 64);
  v += __shfl_xor(v, 8, 64);
  return v;
}
__device__ __forceinline__ float lrelu(float x) { return x > 0.f ? x : 0.2f * x; }

// ---------------- dtype probe ----------------
__global__ void k_detect(const void* emb, int* flag) {
  if (threadIdx.x == 0 && blockIdx.x == 0) {
    const us_t* u = (const us_t*)emb;
    int ok = 1;
    for (int i = 0; i < 128; i++) {
      float v = bf2f((unsigned int)u[i]);
      if (!(fabsf(v) <= 0.13f)) { ok = 0; break; }
    }
    *flag = ok;  // 1 => inputs bf16, 0 => f32
  }
}

// ---------------- fused prep: convert + transpose weights ----------------
struct PrepArgs {
  const void* src[17];
  void* dst[17];
  int n[17];
  int kind[17];   // 0 cvt f32, 1 cvt bf16, 2 g1W T, 3 g2W T, 4 W2 T (192x192)
  int start[18];
};

__global__ void k_prep(PrepArgs pa, const int* __restrict__ flag) {
  int blk = blockIdx.x;
  int s = 0;
  while (s < 16 && blk >= pa.start[s + 1]) s++;
  int i = (blk - pa.start[s]) * 256 + threadIdx.x;
  if (i >= pa.n[s]) return;
  float v = (*flag) ? bf2f((unsigned int)((const us_t*)pa.src[s])[i])
                    : ((const float*)pa.src[s])[i];
  int kind = pa.kind[s];
  if (kind == 0) {
    ((float*)pa.dst[s])[i] = v;
  } else if (kind == 1) {
    ((us_t*)pa.dst[s])[i] = f2bf(v);
  } else if (kind == 2) {  // [3][64][1024] -> [3][1024][64]
    int ii = i >> 16, r = i & 65535, k = r >> 10, col = r & 1023;
    ((us_t*)pa.dst[s])[(ii << 16) + col * 64 + k] = f2bf(v);
  } else if (kind == 3) {  // [3][1024][64] -> [3][64][1024]
    int ii = i >> 16, r = i & 65535, k = r >> 6, col = r & 63;
    ((us_t*)pa.dst[s])[(ii << 16) + col * 1024 + k] = f2bf(v);
  } else {  // [192][192] -> [192][192]^T
    int k = i / 192, col = i % 192;
    ((us_t*)pa.dst[s])[col * 192 + k] = f2bf(v);
  }
}

// ---------------- Waspack: [96 cols][64 k] bf16; col = i*32 + sd*16 + h ----------------
__global__ void k_prepWa(const void* __restrict__ g1Wraw,
                         const float* __restrict__ g1as, const float* __restrict__ g1ad,
                         const int* __restrict__ flag, us_t* __restrict__ Waspack) {
  int gid = blockIdx.x * 256 + threadIdx.x;
  if (gid >= 96 * 64) return;
  int c = gid >> 6, k = gid & 63;
  int i = c >> 5, sd = (c >> 4) & 1, h = c & 15;
  const float* av = (sd ? g1ad : g1as) + i * 1024 + h * 64;
  size_t base = (size_t)i * 65536 + (size_t)k * 1024 + h * 64;
  int isbf = *flag;
  float s = 0.f;
  for (int d = 0; d < 64; d++) {
    float wv = isbf ? bf2f((unsigned int)((const us_t*)g1Wraw)[base + d])
                    : ((const float*)g1Wraw)[base + d];
    s += wv * av[d];
  }
  Waspack[c * 64 + k] = f2bf(s);
}

// ---------------- embedding gather + interest softmax ----------------
__global__ void k_embed(const int* __restrict__ x, const void* __restrict__ embr,
                        const void* __restrict__ wintr, const int* __restrict__ flag,
                        us_t* __restrict__ e_bf, float* __restrict__ g) {
  int gid = blockIdx.x * blockDim.x + threadIdx.x;
  int n = gid >> 6, lane = gid & 63;
  if (n >= NN) return;
  int isbf = *flag;
  size_t ei = (size_t)x[n] * 64 + lane;
  float v = isbf ? bf2f((unsigned int)((const us_t*)embr)[ei]) : ((const float*)embr)[ei];
  e_bf[(size_t)n * 64 + lane] = f2bf(v);
  float w0, w1, w2;
  if (isbf) {
    const us_t* w = (const us_t*)wintr;
    w0 = bf2f(w[lane * 3 + 0]); w1 = bf2f(w[lane * 3 + 1]); w2 = bf2f(w[lane * 3 + 2]);
  } else {
    const float* w = (const float*)wintr;
    w0 = w[lane * 3 + 0]; w1 = w[lane * 3 + 1]; w2 = w[lane * 3 + 2];
  }
  float t0 = wsum(v * w0), t1 = wsum(v * w1), t2 = wsum(v * w2);
  if (lane == 0) {
    float l0 = t0 / 0.1f, l1 = t1 / 0.1f, l2 = t2 / 0.1f;
    float m = fmaxf(l0, fmaxf(l1, l2));
    float p0 = __expf(l0 - m), p1 = __expf(l1 - m), p2 = __expf(l2 - m);
    float inv = 1.0f / (p0 + p1 + p2);
    g[n * 4 + 0] = p0 * inv; g[n * 4 + 1] = p1 * inv;
    g[n * 4 + 2] = p2 * inv; g[n * 4 + 3] = 0.f;
  }
}

// ---------------- compact per-interest CSR build (valid edges only) ----------------
__global__ void k_countv(const int* __restrict__ ei, const float* __restrict__ g,
                         int* __restrict__ countsv) {
  int e = blockIdx.x * 256 + threadIdx.x;
  if (e >= EE) return;
  int s = ei[e], d = ei[EE + e];
  const float thr = 1.0f / 3.0f;
#pragma unroll
  for (int i = 0; i < 3; i++) {
    if (g[s * 4 + i] > thr && g[d * 4 + i] > thr)
      atomicAdd(&countsv[i * NN + d], 1);
  }
}

__global__ void k_scanv(const int* __restrict__ counts, int* __restrict__ offsets) {
  __shared__ int part[256];
  __shared__ int excl[257];
  int t = threadIdx.x;
  int base = t * 192;
  int s = 0;
  for (int j = 0; j < 192; j++) s += counts[base + j];
  part[t] = s;
  __syncthreads();
  if (t == 0) {
    int run = 0;
    for (int j = 0; j < 256; j++) { excl[j] = run; run += part[j]; }
    excl[256] = run;
  }
  __syncthreads();
  int run = excl[t];
  for (int j = 0; j < 192; j++) { offsets[base + j] = run; run += counts[base + j]; }
  if (t == 255) offsets[3 * NN] = excl[256];
}

__global__ void k_fillv(const int* __restrict__ ei, const float* __restrict__ g,
                        const float* __restrict__ eatt,
                        const int* __restrict__ offsetsv, int* __restrict__ fillposv,
                        int2* __restrict__ edgesC, float* __restrict__ easrcP) {
  int e = blockIdx.x * 256 + threadIdx.x;
  if (e >= EE) return;
  int s = ei[e], d = ei[EE + e];
  const float thr = 1.0f / 3.0f;
#pragma unroll
  for (int i = 0; i < 3; i++) {
    float gs = g[s * 4 + i];
    if (gs > thr && g[d * 4 + i] > thr) {
      int pos = offsetsv[i * NN + d] + atomicAdd(&fillposv[i * NN + d], 1);
      edgesC[pos] = make_int2(s, __float_as_int(gs));
      const float* er = &eatt[(size_t)s * 96 + i * 32];
      float* op = &easrcP[(size_t)pos * 16];
#pragma unroll
      for (int h = 0; h < 16; h++) op[h] = gs * er[h];
    }
  }
}

// ---------------- easrc: e[N,64] @ Waspack^T -> eatt[N][96] f32 ----------------
__global__ __launch_bounds__(256) void k_easrc(
    const us_t* __restrict__ e_bf, const us_t* __restrict__ Waspack,
    float* __restrict__ eatt) {
  __shared__ char As[8192];
  int t = threadIdx.x;
  int row0 = blockIdx.x * 64;
  for (int id = t; id < 512; id += 256) {
    int r = id >> 3, c = id & 7;
    uint4 v = *(const uint4*)&e_bf[(size_t)(row0 + r) * 64 + c * 8];
    *(uint4*)(As + r * 128 + ((c ^ (r & 7)) << 4)) = v;
  }
  __syncthreads();
  int wv = t >> 6, L = t & 63, li = L & 15, lq = L >> 4;
#pragma unroll
  for (int ct = 0; ct < 6; ct++) {
    f32x4 acc = {0.f, 0.f, 0.f, 0.f};
#pragma unroll
    for (int ks = 0; ks < 2; ks++) {
      int row = wv * 16 + li;
      bf16x8 af = *(const bf16x8*)(As + row * 128 + (((ks * 4 + lq) ^ (row & 7)) << 4));
      bf16x8 bfr = *(const bf16x8*)(Waspack + (size_t)(ct * 16 + li) * 64 + ks * 32 + lq * 8);
      acc = __builtin_amdgcn_mfma_f32_16x16x32_bf16(af, bfr, acc, 0, 0, 0);
    }
#pragma unroll
    for (int r = 0; r < 4; r++) {
      int row = row0 + wv * 16 + lq * 4 + r;
      eatt[(size_t)row * 96 + ct * 16 + li] = acc[r];
    }
  }
}

// ---------------- FUSED GAT: x-space agg (compact CSR) + per-head W1/relu/W2 ----------------
__global__ __launch_bounds__(256) void k_gat_fused(
    const us_t* __restrict__ e_bf, const float* __restrict__ g,
    const float* __restrict__ eatt, const us_t* __restrict__ g1Wt,
    const us_t* __restrict__ g2Wt, const float* __restrict__ b1all,
    const float* __restrict__ g2as, const float* __restrict__ g2ad,
    const int* __restrict__ offsetsv, const int2* __restrict__ edgesC,
    const float* __restrict__ easrcP,
    float* __restrict__ h2pre, float* __restrict__ a2s, float* __restrict__ a2d) {
  __shared__ char xagg[32 * 2048];     // [32 nodes][16 heads*64 xdims] bf16, swizzled
  __shared__ char Tbuf[2][32 * 128];   // h1 tile per head [32][64] bf16, swizzled
  __shared__ float a2sl[32], a2dl[32];
  int t = threadIdx.x;
  int intr = blockIdx.y;
  int n0 = blockIdx.x * 32;
  int wv = t >> 6, L = t & 63, li = L & 15, lq = L >> 4;
  const us_t* Wt1 = g1Wt + (size_t)intr * 65536;
  const us_t* Wt2 = g2Wt + (size_t)intr * 65536;
  const float* b1 = b1all + intr * 1024;
  const float* as2 = g2as + intr * 64;
  const float* ad2 = g2ad + intr * 64;
  if (t < 32) { a2sl[t] = 0.f; a2dl[t] = 0.f; }
  // ---- Phase A: x-space aggregation, self-anchored softmax, compact edges ----
  int h = L >> 2;
  int doff = (L & 3) * 16;
  for (int k = 0; k < 8; k++) {
    int nl = wv * 8 + k;
    int n = n0 + nl;
    float gn = g[n * 4 + intr];
    float ad = gn * eatt[(size_t)n * 96 + intr * 32 + 16 + h];
    float m = lrelu(gn * eatt[(size_t)n * 96 + intr * 32 + h] + ad);
    float den = 1.f;
    float acc[16];
    {
      const uint4* ep = (const uint4*)&e_bf[(size_t)n * 64 + doff];
      uint4 a = ep[0], b = ep[1];
      acc[0] = gn * bf2f(a.x);  acc[1] = gn * bf2f(a.x >> 16);
      acc[2] = gn * bf2f(a.y);  acc[3] = gn * bf2f(a.y >> 16);
      acc[4] = gn * bf2f(a.z);  acc[5] = gn * bf2f(a.z >> 16);
      acc[6] = gn * bf2f(a.w);  acc[7] = gn * bf2f(a.w >> 16);
      acc[8] = gn * bf2f(b.x);  acc[9] = gn * bf2f(b.x >> 16);
      acc[10] = gn * bf2f(b.y); acc[11] = gn * bf2f(b.y >> 16);
      acc[12] = gn * bf2f(b.z); acc[13] = gn * bf2f(b.z >> 16);
      acc[14] = gn * bf2f(b.w); acc[15] = gn * bf2f(b.w >> 16);
    }
    int beg = offsetsv[intr * NN + n], end = offsetsv[intr * NN + n + 1];
    for (int j = beg; j < end; j++) {
      int2 sg = edgesC[j];
      int s = sg.x;
      float gs = __int_as_float(sg.y);
      float l = lrelu(easrcP[(size_t)j * 16 + h] + ad);
      float p = __expf(l - m);
      den += p;
      float pg = p * gs;
      const uint4* ep = (const uint4*)&e_bf[(size_t)s * 64 + doff];
      uint4 a = ep[0], b = ep[1];
      acc[0] += pg * bf2f(a.x);  acc[1] += pg * bf2f(a.x >> 16);
      acc[2] += pg * bf2f(a.y);  acc[3] += pg * bf2f(a.y >> 16);
      acc[4] += pg * bf2f(a.z);  acc[5] += pg * bf2f(a.z >> 16);
      acc[6] += pg * bf2f(a.w);  acc[7] += pg * bf2f(a.w >> 16);
      acc[8] += pg * bf2f(b.x);  acc[9] += pg * bf2f(b.x >> 16);
      acc[10] += pg * bf2f(b.y); acc[11] += pg * bf2f(b.y >> 16);
      acc[12] += pg * bf2f(b.z); acc[13] += pg * bf2f(b.z >> 16);
      acc[14] += pg * bf2f(b.w); acc[15] += pg * bf2f(b.w >> 16);
    }
    float inv = 1.f / den;
    u32_t w[8];
#pragma unroll
    for (int kk = 0; kk < 8; kk++) {
      w[kk] = (u32_t)f2bf(acc[2 * kk] * inv) | ((u32_t)f2bf(acc[2 * kk + 1] * inv) << 16);
    }
    int c0 = h * 8 + (L & 3) * 2;
    *(uint4*)(xagg + nl * 2048 + ((c0 ^ (nl & 7)) << 4)) = make_uint4(w[0], w[1], w[2], w[3]);
    *(uint4*)(xagg + nl * 2048 + (((c0 + 1) ^ (nl & 7)) << 4)) = make_uint4(w[4], w[5], w[6], w[7]);
  }
  __syncthreads();
  // ---- Phase B: per head: T = relu(xagg_h @ W1_h + b1); h2 += T @ W2_h ----
  int rt = wv & 1, ctb = (wv >> 1) * 2;
  f32x4 acc2[2];
  acc2[0] = {0.f, 0.f, 0.f, 0.f};
  acc2[1] = {0.f, 0.f, 0.f, 0.f};
  for (int hh = 0; hh < 16; hh++) {
    f32x4 c1[2];
    c1[0] = {0.f, 0.f, 0.f, 0.f};
    c1[1] = {0.f, 0.f, 0.f, 0.f};
#pragma unroll
    for (int ks = 0; ks < 2; ks++) {
      int row = rt * 16 + li;
      int ca = hh * 8 + ks * 4 + lq;
      bf16x8 af = *(const bf16x8*)(xagg + row * 2048 + ((ca ^ (row & 7)) << 4));
#pragma unroll
      for (int c2 = 0; c2 < 2; c2++) {
        int oc = hh * 64 + (ctb + c2) * 16 + li;
        bf16x8 bfr = *(const bf16x8*)(Wt1 + (size_t)oc * 64 + ks * 32 + lq * 8);
        c1[c2] = __builtin_amdgcn_mfma_f32_16x16x32_bf16(af, bfr, c1[c2], 0, 0, 0);
      }
    }
    char* Tb = Tbuf[hh & 1];
#pragma unroll
    for (int c2 = 0; c2 < 2; c2++) {
      int col = (ctb + c2) * 16 + li;
      float bv = b1[hh * 64 + col];
#pragma unroll
      for (int r = 0; r < 4; r++) {
        int row = rt * 16 + lq * 4 + r;
        float tv = fmaxf(c1[c2][r] + bv, 0.f);
        int cc = (col * 2) >> 4;
        *(us_t*)(Tb + row * 128 + ((cc ^ (row & 7)) << 4) + ((col * 2) & 15)) = f2bf(tv);
      }
    }
    __syncthreads();
#pragma unroll
    for (int ks = 0; ks < 2; ks++) {
      int row = rt * 16 + li;
      int cc = ks * 4 + lq;
      bf16x8 af2 = *(const bf16x8*)(Tb + row * 128 + ((cc ^ (row & 7)) << 4));
#pragma unroll
      for (int c2 = 0; c2 < 2; c2++) {
        int oc = (ctb + c2) * 16 + li;
        bf16x8 bfr = *(const bf16x8*)(Wt2 + (size_t)oc * 1024 + hh * 64 + ks * 32 + lq * 8);
        acc2[c2] = __builtin_amdgcn_mfma_f32_16x16x32_bf16(af2, bfr, acc2[c2], 0, 0, 0);
      }
    }
  }
  // ---- epilogue: write h2pre, accumulate a2s/a2d ----
  float ps[4] = {0.f, 0.f, 0.f, 0.f}, pd[4] = {0.f, 0.f, 0.f, 0.f};
#pragma unroll
  for (int c2 = 0; c2 < 2; c2++) {
    int col = (ctb + c2) * 16 + li;
    float asv = as2[col], adv = ad2[col];
#pragma unroll
    for (int r = 0; r < 4; r++) {
      int row = rt * 16 + lq * 4 + r;
      float v = acc2[c2][r];
      h2pre[((size_t)intr * NN + n0 + row) * 64 + col] = v;
      ps[r] += v * asv;
      pd[r] += v * adv;
    }
  }
#pragma unroll
  for (int r = 0; r < 4; r++) { ps[r] = redu16(ps[r]); pd[r] = redu16(pd[r]); }
  if (li == 0) {
#pragma unroll
    for (int r = 0; r < 4; r++) {
      atomicAdd(&a2sl[rt * 16 + lq * 4 + r], ps[r]);
      atomicAdd(&a2dl[rt * 16 + lq * 4 + r], pd[r]);
    }
  }
  __syncthreads();
  if (t < 32) {
    a2s[(size_t)intr * NN + n0 + t] = a2sl[t];
    a2d[(size_t)intr * NN + n0 + t] = a2dl[t];
  }
}

// ---------------- GAT2 aggregation (compact CSR, self-anchored) -> sess ----------------
__global__ void k_gat2_agg(const float* __restrict__ h2pre_a,
                           const float* __restrict__ a2s_a, const float* __restrict__ a2d_a,
                           const float* __restrict__ b2all,
                           const int* __restrict__ offsetsv,
                           const int2* __restrict__ edgesC, float* __restrict__ sess) {
  int intr = blockIdx.y;
  int gid = blockIdx.x * blockDim.x + threadIdx.x;
  int n = gid >> 6, lane = gid & 63;
  if (n >= NN) return;
  const float* h2pre = h2pre_a + (size_t)intr * NN * 64;
  const float* a2s = a2s_a + (size_t)intr * NN;
  const float* a2d = a2d_a + (size_t)intr * NN;
  const float* b2 = b2all + intr * 64;
  float ad = a2d[n];
  float m = lrelu(a2s[n] + ad);  // self anchor; softmax shift-invariant
  float den = 1.f;
  float acc = h2pre[(size_t)n * 64 + lane];
  int beg = offsetsv[intr * NN + n], end = offsetsv[intr * NN + n + 1];
  for (int j = beg; j < end; j++) {
    int s = edgesC[j].x;
    float l = lrelu(a2s[s] + ad);
    float p = __expf(l - m);
    den += p;
    acc += p * h2pre[(size_t)s * 64 + lane];
  }
  sess[(size_t)n * 192 + intr * 64 + lane] = acc / den + b2[lane];
}

// ---------------- scoring ----------------
__global__ __launch_bounds__(192) void k_vq1(
    const float* __restrict__ sess,
    const float* __restrict__ W1w, const float* __restrict__ W1b,
    float* __restrict__ vn, float* __restrict__ vq1) {
  __shared__ float row[192];
  int b = blockIdx.x, j = threadIdx.x;
  int li = b * 32 + 31;  // batch = repeat(arange(B),32)
  float v = sess[(size_t)li * 192 + j];
  row[j] = v;
  vn[b * 192 + j] = v;
  __syncthreads();
  float acc = W1b[j];
  for (int k = 0; k < 192; k++) acc += row[k] * W1w[k * 192 + j];
  vq1[b * 192 + j] = acc;
}

__global__ __launch_bounds__(256) void k_alpha_sg_mfma(
    const float* __restrict__ sess, const float* __restrict__ vq1,
    const us_t* __restrict__ W2T, const float* __restrict__ W2b,
    const float* __restrict__ qw, const float* __restrict__ qb,
    float* __restrict__ sg) {
  __shared__ char As[64 * 512];
  __shared__ float vq_l[2 * 192];
  __shared__ float w2b_l[192], qw_l[192];
  __shared__ float sg_l[2 * 192];
  int t = threadIdx.x;
  int n0 = blockIdx.x * 64;
  if (t < 192) { w2b_l[t] = W2b[t]; qw_l[t] = qw[t]; }
  for (int id = t; id < 384; id += 256) {
    sg_l[id] = 0.f;
    vq_l[id] = vq1[(size_t)(blockIdx.x * 2) * 192 + id];
  }
  for (int id = t; id < 1536; id += 256) {
    int r = id / 24, c = id % 24;
    const float* p = &sess[(size_t)(n0 + r) * 192 + c * 8];
    float4 f0 = *(const float4*)p;
    float4 f1 = *(const float4*)(p + 4);
    u32_t w0 = (u32_t)f2bf(f0.x) | ((u32_t)f2bf(f0.y) << 16);
    u32_t w1 = (u32_t)f2bf(f0.z) | ((u32_t)f2bf(f0.w) << 16);
    u32_t w2 = (u32_t)f2bf(f1.x) | ((u32_t)f2bf(f1.y) << 16);
    u32_t w3 = (u32_t)f2bf(f1.z) | ((u32_t)f2bf(f1.w) << 16);
    *(uint4*)(As + r * 512 + ((c ^ (r & 7)) << 4)) = make_uint4(w0, w1, w2, w3);
  }
  __syncthreads();
  int wv = t >> 6, lane = t & 63, li = lane & 15, lq = lane >> 4;
  int sl = wv >> 1;
  f32x4 acc[12];
#pragma unroll
  for (int sub = 0; sub < 12; sub++) acc[sub] = {0.f, 0.f, 0.f, 0.f};
#pragma unroll
  for (int ks = 0; ks < 6; ks++) {
    int r = wv * 16 + li;
    bf16x8 af = *(const bf16x8*)(As + r * 512 + (((ks * 4 + lq) ^ (r & 7)) << 4));
#pragma unroll
    for (int sub = 0; sub < 12; sub++) {
      bf16x8 bfr = *(const bf16x8*)&W2T[(size_t)(sub * 16 + li) * 192 + ks * 32 + lq * 8];
      acc[sub] = __builtin_amdgcn_mfma_f32_16x16x32_bf16(af, bfr, acc[sub], 0, 0, 0);
    }
  }
  float qbv = qb[0];
  float s_part[12];
#pragma unroll
  for (int sub = 0; sub < 12; sub++) s_part[sub] = 0.f;
#pragma unroll
  for (int rr = 0; rr < 4; rr++) {
    int n = n0 + wv * 16 + lq * 4 + rr;
    float ap = 0.f;
    float sv[12];
#pragma unroll
    for (int sub = 0; sub < 12; sub++) {
      int col = sub * 16 + li;
      float q = vq_l[sl * 192 + col] + acc[sub][rr] + w2b_l[col];
      float sgm = 1.f / (1.f + __expf(-q));
      ap += sgm * qw_l[col];
      sv[sub] = sess[(size_t)n * 192 + col];
    }
    ap = redu16(ap);
    float alpha = ap + qbv;
#pragma unroll
    for (int sub = 0; sub < 12; sub++) s_part[sub] += alpha * sv[sub];
  }
#pragma unroll
  for (int sub = 0; sub < 12; sub++) {
    float v = s_part[sub];
    v += __shfl_xor(v, 16, 64);
    v += __shfl_xor(v, 32, 64);
    if (lq == 0) atomicAdd(&sg_l[sl * 192 + sub * 16 + li], v);
  }
  __syncthreads();
  for (int id = t; id < 384; id += 256)
    sg[(size_t)(blockIdx.x * 2) * 192 + id] = sg_l[id];
}

__global__ __launch_bounds__(192) void k_sh(
    const float* __restrict__ vn, const float* __restrict__ sg,
    const float* __restrict__ W3w, const float* __restrict__ W3b,
    float* __restrict__ sh) {
  __shared__ float row[384];
  int b = blockIdx.x, j = threadIdx.x;
  row[j] = vn[b * 192 + j];
  row[192 + j] = sg[b * 192 + j];
  __syncthreads();
  float acc = W3b[j];
  for (int k = 0; k < 384; k++) acc += row[k] * W3w[k * 192 + j];
  sh[b * 192 + j] = acc;
}

// ---------------- final MFMA ----------------
__global__ __launch_bounds__(256) void k_final_mfma(
    const float* __restrict__ sh, const us_t* __restrict__ emb_bf,
    void* __restrict__ out, const int* __restrict__ flag) {
  __shared__ uint4 AsU[384];
  __shared__ uint4 BsU[2048];
  char* As = (char*)AsU;
  char* Bs = (char*)BsU;
  int t = threadIdx.x;
  int v0 = blockIdx.x * 256, b0 = blockIdx.y * 16;
  for (int id = t; id < 384; id += 256) {
    int i2 = id >> 7, rem = id & 127, r = rem >> 3, c = rem & 7;
    const float* p = &sh[(size_t)(b0 + r) * 192 + i2 * 64 + c * 8];
    float4 f0 = *(const float4*)p;
    float4 f1 = *(const float4*)(p + 4);
    u32_t w0 = (u32_t)f2bf(f0.x) | ((u32_t)f2bf(f0.y) << 16);
    u32_t w1 = (u32_t)f2bf(f0.z) | ((u32_t)f2bf(f0.w) << 16);
    u32_t w2 = (u32_t)f2bf(f1.x) | ((u32_t)f2bf(f1.y) << 16);
    u32_t w3 = (u32_t)f2bf(f1.z) | ((u32_t)f2bf(f1.w) << 16);
    *(uint4*)(As + i2 * 2048 + r * 128 + ((c ^ (r & 7)) << 4)) = make_uint4(w0, w1, w2, w3);
  }
  for (int id = t; id < 2048; id += 256) {
    int vr = id >> 3, c = id & 7;
    uint4 v = *(const uint4*)&emb_bf[(size_t)(v0 + vr) * 64 + c * 8];
    *(uint4*)(Bs + vr * 128 + ((c ^ (vr & 7)) << 4)) = v;
  }
  __syncthreads();
  int wv = t >> 6, lane = t & 63, li = lane & 15, lq = lane >> 4;
  int cb = wv * 64;
  int isbf = *flag;
  f32x4 acc[3][4];
#pragma unroll
  for (int i = 0; i < 3; i++)
#pragma unroll
    for (int sub = 0; sub < 4; sub++) acc[i][sub] = {0.f, 0.f, 0.f, 0.f};
#pragma unroll
  for (int ks = 0; ks < 2; ks++) {
    bf16x8 bfr[4];
#pragma unroll
    for (int sub = 0; sub < 4; sub++) {
      int vr = cb + sub * 16 + li;
      bfr[sub] = *(const bf16x8*)(Bs + vr * 128 + ((((ks << 2) | lq) ^ (vr & 7)) << 4));
    }
#pragma unroll
    for (int i = 0; i < 3; i++) {
      bf16x8 af = *(const bf16x8*)(As + i * 2048 + li * 128 + ((((ks << 2) | lq) ^ (li & 7)) << 4));
#pragma unroll
      for (int sub = 0; sub < 4; sub++)
        acc[i][sub] = __builtin_amdgcn_mfma_f32_16x16x32_bf16(af, bfr[sub], acc[i][sub], 0, 0, 0);
    }
  }
#pragma unroll
  for (int sub = 0; sub < 4; sub++) {
    int col = v0 + cb + sub * 16 + li;
#pragma unroll
    for (int rr = 0; rr < 4; rr++) {
      float o = fmaxf(fmaxf(acc[0][sub][rr], acc[1][sub][rr]), acc[2][sub][rr]);
      int b = b0 + lq * 4 + rr;
      if (isbf) ((us_t*)out)[(size_t)b * VV + col] = f2bf(o);
      else ((float*)out)[(size_t)b * VV + col] = o;
    }
  }
}

// ---------------- launcher ----------------
extern "C" void kernel_launch(void* const* d_in, const int* in_sizes, int n_in,
                              void* d_out, int out_size, void* d_ws, size_t ws_size,
                              hipStream_t stream) {
  if (n_in < 21) return;
  const int* x = (const int*)d_in[0];
  const int* ei = (const int*)d_in[1];

  char* ws = (char*)d_ws;
  size_t off = 0;
  auto A = [&](size_t bytes) -> char* {
    char* p = ws + off;
    off += (bytes + 255) & ~(size_t)255;
    return p;
  };
  int* flag = (int*)A(4);
  us_t* emb_bf = (us_t*)A((size_t)VV * 64 * 2);
  us_t* e_bf = (us_t*)A((size_t)NN * 64 * 2);
  us_t* g1Wt = (us_t*)A((size_t)3 * 65536 * 2);
  us_t* g2Wt = (us_t*)A((size_t)3 * 65536 * 2);
  us_t* W2T = (us_t*)A((size_t)36864 * 2);
  us_t* Waspack = (us_t*)A((size_t)96 * 64 * 2);
  float* eatt = (float*)A((size_t)NN * 96 * 4);
  float* c_g1as = (float*)A(3072 * 4);
  float* c_g1ad = (float*)A(3072 * 4);
  float* c_g1b = (float*)A(3072 * 4);
  float* c_g2as = (float*)A(192 * 4);
  float* c_g2ad = (float*)A(192 * 4);
  float* c_g2b = (float*)A(192 * 4);
  float* c_W1w = (float*)A(36864 * 4);
  float* c_W1b = (float*)A(192 * 4);
  float* c_W2b = (float*)A(192 * 4);
  float* c_qw = (float*)A(192 * 4);
  float* c_qb = (float*)A(4);
  float* c_W3w = (float*)A(73728 * 4);
  float* c_W3b = (float*)A(192 * 4);
  float* g_buf = (float*)A((size_t)NN * 4 * 4);
  float* h2pre = (float*)A((size_t)3 * NN * 64 * 4);
  float* a2s = (float*)A((size_t)3 * NN * 4);
  float* a2d = (float*)A((size_t)3 * NN * 4);
  float* sess = (float*)A((size_t)NN * 192 * 4);
  float* vq1 = (float*)A((size_t)BB * 192 * 4);
  float* sg = (float*)A((size_t)BB * 192 * 4);
  float* vn = (float*)A((size_t)BB * 192 * 4);
  float* shb = (float*)A((size_t)BB * 192 * 4);
  int* countsv = (int*)A((size_t)3 * NN * 4);
  int* offsetsv = (int*)A((size_t)(3 * NN + 1) * 4);
  int* fillposv = (int*)A((size_t)3 * NN * 4);
  int2* edgesC = (int2*)A((size_t)3 * EE * 8);
  float* easrcP = (float*)A((size_t)3 * EE * 16 * 4);
  if (off > ws_size) return;

  hipMemsetAsync(countsv, 0, 3 * NN * 4, stream);
  hipMemsetAsync(fillposv, 0, 3 * NN * 4, stream);

  k_detect<<<1, 64, 0, stream>>>(d_in[3], flag);

  PrepArgs pa;
  int nb = 0, idx = 0;
  auto SEC = [&](const void* s, void* d, int n, int kind) {
    pa.src[idx] = s; pa.dst[idx] = d; pa.n[idx] = n; pa.kind[idx] = kind;
    pa.start[idx] = nb; nb += (n + 255) / 256; idx++;
  };
  SEC(d_in[3], emb_bf, VV * 64, 1);
  SEC(d_in[5], g1Wt, 196608, 2);
  SEC(d_in[9], g2Wt, 196608, 3);
  SEC(d_in[15], W2T, 36864, 4);
  SEC(d_in[6], c_g1as, 3072, 0);
  SEC(d_in[7], c_g1ad, 3072, 0);
  SEC(d_in[8], c_g1b, 3072, 0);
  SEC(d_in[10], c_g2as, 192, 0);
  SEC(d_in[11], c_g2ad, 192, 0);
  SEC(d_in[12], c_g2b, 192, 0);
  SEC(d_in[13], c_W1w, 36864, 0);
  SEC(d_in[14], c_W1b, 192, 0);
  SEC(d_in[16], c_W2b, 192, 0);
  SEC(d_in[17], c_qw, 192, 0);
  SEC(d_in[18], c_qb, 1, 0);
  SEC(d_in[19], c_W3w, 73728, 0);
  SEC(d_in[20], c_W3b, 192, 0);
  pa.start[17] = nb;
  k_prep<<<nb, 256, 0, stream>>>(pa, flag);
  k_prepWa<<<24, 256, 0, stream>>>(d_in[5], c_g1as, c_g1ad, flag, Waspack);

  k_embed<<<NN * 64 / 256, 256, 0, stream>>>(x, d_in[3], d_in[4], flag, e_bf, g_buf);
  k_easrc<<<NN / 64, 256, 0, stream>>>(e_bf, Waspack, eatt);
  k_countv<<<EE / 256, 256, 0, stream>>>(ei, g_buf, countsv);
  k_scanv<<<1, 256, 0, stream>>>(countsv, offsetsv);
  k_fillv<<<EE / 256, 256, 0, stream>>>(ei, g_buf, eatt, offsetsv, fillposv,
                                        edgesC, easrcP);

  k_gat_fused<<<dim3(NN / 32, 3), 256, 0, stream>>>(
      e_bf, g_buf, eatt, g1Wt, g2Wt, c_g1b, c_g2as, c_g2ad,
      offsetsv, edgesC, easrcP, h2pre, a2s, a2d);
  k_gat2_agg<<<dim3(NN * 64 / 256, 3), 256, 0, stream>>>(
      h2pre, a2s, a2d, c_g2b, offsetsv, edgesC, sess);

  k_vq1<<<BB, 192, 0, stream>>>(sess, c_W1w, c_W1b, vn, vq1);
  k_alpha_sg_mfma<<<NN / 64, 256, 0, stream>>>(sess, vq1, W2T, c_W2b, c_qw, c_qb, sg);
  k_sh<<<BB, 192, 0, stream>>>(vn, sg, c_W3w, c_W3b, shb);
  k_final_mfma<<<dim3(VV / 256, BB / 16), 256, 0, stream>>>(shb, emb_bf, d_out, flag);
}